// Round 6
// baseline (1096.355 us; speedup 1.0000x reference)
//
#include <hip/hip_runtime.h>
#include <hip/hip_bf16.h>
#include <math.h>

typedef __hip_bfloat16 bf16;

typedef __attribute__((ext_vector_type(8))) short bfrag;
typedef __attribute__((ext_vector_type(4))) float f32x4;
union FragU { bfrag s; uint2 d[2]; unsigned int u[4]; };

static __device__ __forceinline__ float b2f(bf16 x){ return __bfloat162float(x); }
// pack two floats into a bf16x2 uint
static __device__ __forceinline__ unsigned int f2b2(float lo, float hi){
  bf16 l = __float2bfloat16(lo), h = __float2bfloat16(hi);
  unsigned short lb, hb;
  __builtin_memcpy(&lb, &l, 2); __builtin_memcpy(&hb, &h, 2);
  return (unsigned int)lb | ((unsigned int)hb << 16);
}
static __device__ __forceinline__ void sto(float* p, size_t i, float v){ p[i] = v; }
static __device__ __forceinline__ void sto(bf16* p, size_t i, float v){ p[i] = __float2bfloat16(v); }

// async global->LDS DMA, 16B per lane (fire-and-forget, vmcnt-tracked)
static __device__ __forceinline__ void gld_lds16(const void* g, void* l){
  __builtin_amdgcn_global_load_lds(
      (const __attribute__((address_space(1))) unsigned int*)g,
      (__attribute__((address_space(3))) unsigned int*)l,
      16, 0, 0);
}

// ---------------- workspace layout (bytes) ----------------
constexpr size_t MiB = 1ull << 20;
constexpr size_t OFF_C1   = 0;         // bf16 [1600,32,20,20] 40.96 MB
constexpr size_t OFF_C2   = 41*MiB;    // bf16 [1600,64,9,9]
constexpr size_t OFF_C3   = 58*MiB;    // bf16 [1600,3136]
constexpr size_t OFF_SE   = 69*MiB;    // f32  [1600,128]
constexpr size_t OFF_H    = 0;         // f32  [4800,128]
constexpr size_t OFF_XA   = 3*MiB;     // bf16 [4800,128]
constexpr size_t OFF_NORM = 6*MiB;     // bf16 [4800,128]
constexpr size_t OFF_QKV  = 9*MiB;     // bf16 [4800,384]
constexpr size_t OFF_Y    = 17*MiB;    // bf16 [4800,128]
constexpr size_t OFF_H1   = 20*MiB;    // f32  [4800,128]
constexpr size_t OFF_MLPH = 23*MiB;    // bf16 [4800,512]
constexpr size_t OFF_ADH  = 33*MiB;    // bf16 [4800,64]
// conv3 weight table (bf16 [64][576], k = tap*64+c) parked at offset 0:
// written AFTER conv2 (c1 data dead), consumed by conv3, then clobbered by token/h.
constexpr size_t OFF_WT   = 0;
// conv1 weight table (bf16 [32][256], linear cvt) parked at OFF_C2:
// written BEFORE conv1 (c2 region dead), consumed by conv1, overwritten by conv2.
constexpr size_t OFF_WT1  = OFF_C2;

// ---------------- conv1 weight repack: f32 [32][256] -> bf16 [32][256] (same layout) ----------------
__global__ __launch_bounds__(256) void c1wt_kernel(const float* __restrict__ w, bf16* __restrict__ wt)
{
  int i = blockIdx.x*256 + threadIdx.x;   // 8192
  wt[i] = __float2bfloat16(w[i]);
}

// ================= conv1 via implicit-im2col MFMA, quarter-image DMA tiles =================
// x f32 [1600,4,84,84] -> relu -> bf16 [1600,32,20,20]
// GEMM per image: M=400, N=32, K=256 (c*64+ky*8+kx), split into 4 blocks of
// 5 output rows each (M=100). Output rows hf*5..hf*5+4 need input rows
// hf*20 .. hf*20+23  ==> 24 rows/channel (R5 staged 23: off-by-one, failed).
// R5 theory: DMA staging (per-wave MLP) + 31.5KB LDS (5 blk/CU, cross-block
// stage/compute overlap) + small acc[2][2] (no VGPR squeeze).
__global__ __launch_bounds__(256) void conv1_kernel(
    const float* __restrict__ x, const bf16* __restrict__ wt,
    const float* __restrict__ bias, bf16* __restrict__ out)
{
  __shared__ float xsf[4*24*84];    // 32256 B DMA dest; reused as bf16 out-stage [32][104]
  int bi = blockIdx.x;
  int b = bi >> 2, hf = bi & 3;     // image, quarter (output rows hf*5 .. hf*5+4)
  int t = threadIdx.x;
  // DMA stage: 4 channels x 24 rows (= 504 16B-chunks per channel), linear LDS dest
  const char* xb = (const char*)(x + (size_t)b*28224 + hf*20*84);
  for (int i = t; i < 2016; i += 256){
    int c = i / 504, rem = i % 504;
    gld_lds16(xb + (size_t)c*28224 + (size_t)rem*16, ((char*)xsf) + (size_t)i*16);
  }
  __syncthreads();
  int lane = t & 63, wave = t >> 6;
  int quad = lane >> 4, r16 = lane & 15;
  f32x4 acc[2][2];
  #pragma unroll
  for (int i = 0; i < 2; ++i)
    #pragma unroll
    for (int j = 0; j < 2; ++j) acc[i][j] = (f32x4){0.f,0.f,0.f,0.f};
  for (int kc = 0; kc < 8; ++kc){
    int c = kc >> 1, ky = (kc & 1)*4 + quad;
    FragU bf_[2];
    #pragma unroll
    for (int tn = 0; tn < 2; ++tn){
      uint4 wv = *(const uint4*)(wt + (tn*16 + r16)*256 + kc*32 + quad*8);
      bf_[tn].u[0] = wv.x; bf_[tn].u[1] = wv.y; bf_[tn].u[2] = wv.z; bf_[tn].u[3] = wv.w;
    }
    #pragma unroll
    for (int i = 0; i < 2; ++i){
      int tile = i*4 + wave;          // tiles 0..6 over 4 waves (wave-uniform guard)
      if (tile < 7){
        int m = tile*16 + r16; if (m > 99) m = 99;     // clamp pad lanes
        int oy = m / 20, ox = m % 20;                  // local oy 0..4
        const float* p = xsf + (c*24 + 4*oy + ky)*84 + 4*ox;
        float4 fa = *(const float4*)p;        // ds_read_b128, 16B-aligned
        float4 fb = *(const float4*)(p + 4);
        FragU a;
        a.u[0] = f2b2(fa.x, fa.y); a.u[1] = f2b2(fa.z, fa.w);
        a.u[2] = f2b2(fb.x, fb.y); a.u[3] = f2b2(fb.z, fb.w);
        acc[i][0] = __builtin_amdgcn_mfma_f32_16x16x32_bf16(a.s, bf_[0].s, acc[i][0], 0, 0, 0);
        acc[i][1] = __builtin_amdgcn_mfma_f32_16x16x32_bf16(a.s, bf_[1].s, acc[i][1], 0, 0, 0);
      }
    }
  }
  __syncthreads();   // compute reads done; reuse xsf as bf16 out-stage [32][104]
  bf16* ost = (bf16*)xsf;
  #pragma unroll
  for (int i = 0; i < 2; ++i){
    int tile = i*4 + wave;
    if (tile < 7){
      int m0 = tile*16 + quad*4;
      if (m0 < 100){
        #pragma unroll
        for (int tn = 0; tn < 2; ++tn){
          int oc = tn*16 + r16;
          float bb = bias[oc];
          float v0 = fmaxf(acc[i][tn][0] + bb, 0.f);
          float v1 = fmaxf(acc[i][tn][1] + bb, 0.f);
          float v2 = fmaxf(acc[i][tn][2] + bb, 0.f);
          float v3 = fmaxf(acc[i][tn][3] + bb, 0.f);
          *(uint2*)(ost + oc*104 + m0) = make_uint2(f2b2(v0, v1), f2b2(v2, v3));
        }
      }
    }
  }
  __syncthreads();
  bf16* outp = out + (size_t)b*12800 + hf*100;
  for (int e = t; e < 800; e += 256){       // 32 oc * 25 uint2-groups of 4
    int oc = e / 25, g = e % 25;
    *(uint2*)(outp + oc*400 + g*4) = *(const uint2*)(ost + oc*104 + g*4);
  }
}

// ================= conv2 via implicit-im2col MFMA =================
// x bf16 [1600,32,20,20] -> relu -> bf16 [1600,64,9,9]
// GEMM per image: M=81 (pad 96), N=64, K=512 (c*16+ky*4+kx)
__global__ __launch_bounds__(256) void conv2_kernel(
    const bf16* __restrict__ x, const float* __restrict__ w,
    const float* __restrict__ bias, bf16* __restrict__ out)
{
  __shared__ bf16 xs2[32*20*24];    // [c][row][24 pad]; reused as out-stage [64][81]
  int b = blockIdx.x;
  int t = threadIdx.x;
  const unsigned int* xb = (const unsigned int*)(x + (size_t)b*12800);
  for (int p = t; p < 6400; p += 256){
    int c = p / 200, rem = p % 200;
    int r = rem / 10, cp = rem % 10;
    ((unsigned int*)xs2)[((c*20 + r)*24 + 2*cp) >> 1] = xb[p];
  }
  __syncthreads();
  int lane = t & 63, wave = t >> 6;
  int quad = lane >> 4, r16 = lane & 15;
  int oc = wave*16 + r16;     // wave owns one oc-tile
  f32x4 acc[6];
  #pragma unroll
  for (int i = 0; i < 6; ++i) acc[i] = (f32x4){0.f,0.f,0.f,0.f};
  for (int kc = 0; kc < 16; ++kc){
    const float* wp = w + oc*512 + kc*32 + quad*8;
    float4 wa = ((const float4*)wp)[0], wb = ((const float4*)wp)[1];
    FragU bfr;
    bfr.u[0] = f2b2(wa.x, wa.y); bfr.u[1] = f2b2(wa.z, wa.w);
    bfr.u[2] = f2b2(wb.x, wb.y); bfr.u[3] = f2b2(wb.z, wb.w);
    int c = kc*2 + (quad >> 1);
    int ky0 = (quad & 1)*2;
    #pragma unroll
    for (int tile = 0; tile < 6; ++tile){
      int m = tile*16 + r16; if (m > 80) m = 80;
      int oy = m / 9, ox = m % 9;
      int idx1 = (c*20 + 2*oy + ky0)*24 + 2*ox;
      const unsigned int* q1 = (const unsigned int*)(xs2 + idx1);
      const unsigned int* q2 = (const unsigned int*)(xs2 + idx1 + 24);
      FragU a;
      a.u[0] = q1[0]; a.u[1] = q1[1];
      a.u[2] = q2[0]; a.u[3] = q2[1];
      acc[tile] = __builtin_amdgcn_mfma_f32_16x16x32_bf16(a.s, bfr.s, acc[tile], 0, 0, 0);
    }
  }
  __syncthreads();   // staging reads done; reuse xs2 as out-stage [64][81]
  float bb = bias[oc];
  #pragma unroll
  for (int tile = 0; tile < 6; ++tile){
    #pragma unroll
    for (int r = 0; r < 4; ++r){
      int m = tile*16 + quad*4 + r;
      if (m < 81){
        float v = fmaxf(acc[tile][r] + bb, 0.f);
        xs2[oc*81 + m] = __float2bfloat16(v);
      }
    }
  }
  __syncthreads();
  const unsigned int* lsu = (const unsigned int*)xs2;
  unsigned int* op = (unsigned int*)(out + (size_t)b*5184);
  for (int e = t; e < 2592; e += 256) op[e] = lsu[e];
}

// ---------------- conv3 weight repack: f32 [64][64][3][3] -> bf16 [64][576] k'=tap*64+c ----------------
__global__ __launch_bounds__(256) void wt_kernel(const float* __restrict__ w, bf16* __restrict__ wt)
{
  int o = blockIdx.x*256 + threadIdx.x;   // 36864 = 144*256
  int oc = o / 576, r = o % 576;
  int tap = r >> 6, c = r & 63;
  wt[o] = __float2bfloat16(w[oc*576 + c*9 + tap]);
}

// ================= conv3 via implicit-im2col MFMA =================
// x bf16 [1600,64,9,9] -> relu -> bf16 [1600,64,7,7]->[1600,3136]
// GEMM per image: M=49 (pad 64), N=64, K=576, k' = (ky*3+kx)*64 + c (tap-major).
__global__ __launch_bounds__(256) void conv3_kernel(
    const bf16* __restrict__ x, const bf16* __restrict__ wt,
    const float* __restrict__ bias, bf16* __restrict__ out)
{
  __shared__ ushort lin[5184];      // image in native [c][81] layout; reused as out-stage [64][49]
  __shared__ ushort xt[81*72];      // [p][c], stride 72 (pad cols 64..71 unread)
  int b = blockIdx.x;
  int t = threadIdx.x;
  // pass 1: coalesced copy global -> LDS (raw bf16 bits)
  const uint2* xb = (const uint2*)(x + (size_t)b*5184);
  for (int i = t; i < 1296; i += 256) ((uint2*)lin)[i] = xb[i];
  __syncthreads();
  // pass 2: transpose in LDS: xt[p*72+c] = x[c][p]
  for (int e = t; e < 5184; e += 256){
    int c = e & 63, p = e >> 6;     // 5184 = 81*64
    xt[p*72 + c] = lin[c*81 + p];
  }
  __syncthreads();
  int lane = t & 63, wv = t >> 6;
  int quad = lane >> 4, r16 = lane & 15;
  int m = wv*16 + r16;              // A-row this lane feeds
  int pos = m < 49 ? m : 48;        // clamp pad rows (results discarded)
  int pb = (pos/7)*9 + (pos%7);     // output position -> input base position
  const ushort* abase = xt + pb*72 + quad*8;      // loop-invariant per lane
  const bf16* wb0 = wt + (size_t)r16*576 + quad*8;
  f32x4 acc[4];
  #pragma unroll
  for (int tn = 0; tn < 4; ++tn) acc[tn] = (f32x4){0.f,0.f,0.f,0.f};
  #pragma unroll 3
  for (int kc = 0; kc < 18; ++kc){
    int tap = kc >> 1;
    int toff = (tap/3)*9 + (tap%3);               // ky*9+kx (wave-uniform)
    int soff = toff*72 + (kc & 1)*32;
    FragU a;
    uint4 av = *(const uint4*)(abase + soff);     // 16B-aligned: 144B row stride, 16B col
    a.u[0] = av.x; a.u[1] = av.y; a.u[2] = av.z; a.u[3] = av.w;
    #pragma unroll
    for (int tn = 0; tn < 4; ++tn){
      uint4 bv = *(const uint4*)(wb0 + tn*9216 + kc*32);
      FragU bfr;
      bfr.u[0] = bv.x; bfr.u[1] = bv.y; bfr.u[2] = bv.z; bfr.u[3] = bv.w;
      acc[tn] = __builtin_amdgcn_mfma_f32_16x16x32_bf16(a.s, bfr.s, acc[tn], 0, 0, 0);
    }
  }
  // epilogue: bias+relu, stage to lin [64][49], then coalesced store
  __syncthreads();
  #pragma unroll
  for (int tn = 0; tn < 4; ++tn){
    int oc = tn*16 + r16;
    float bb = bias[oc];
    #pragma unroll
    for (int r = 0; r < 4; ++r){
      int p = wv*16 + quad*4 + r;   // C-layout row
      if (p < 49){
        bf16 v = __float2bfloat16(fmaxf(acc[tn][r] + bb, 0.f));
        ushort u; __builtin_memcpy(&u, &v, 2);
        lin[oc*49 + p] = u;
      }
    }
  }
  __syncthreads();
  uint2* op = (uint2*)(out + (size_t)b*3136);
  for (int e = t; e < 784; e += 256) op[e] = ((const uint2*)lin)[e];
}

// ================= generic MFMA GEMM =================
// out = ACT(X @ W^T + bias) + add_scale*add;  X bf16 [M,K], W f32 [N,K]
// M%64==0, N%64==0, K%32==0. ACT: 0 none, 1 tanh, 2 gelu, 3 relu. OT: float or bf16.
template<int ACT, typename OT>
__global__ __launch_bounds__(256) void mgemm(
    const bf16* __restrict__ X, const float* __restrict__ W,
    const float* __restrict__ bias, const float* __restrict__ add, float add_scale,
    OT* __restrict__ out, int M, int N, int K)
{
  __shared__ bf16 Xs[64*40];
  __shared__ bf16 Ws[64*40];
  int nb = N >> 6;
  int bn = (blockIdx.x % nb) << 6;
  int bm = (blockIdx.x / nb) << 6;
  int t = threadIdx.x;
  int lane = t & 63, wave = t >> 6;
  int mw = wave >> 1, nw = wave & 1;
  int quad = lane >> 4, r16 = lane & 15;
  int srow = t >> 2, scol = (t & 3)*8;
  f32x4 acc[2][2];
  #pragma unroll
  for (int i = 0; i < 2; ++i)
    #pragma unroll
    for (int j = 0; j < 2; ++j) acc[i][j] = (f32x4){0.f,0.f,0.f,0.f};
  for (int k0 = 0; k0 < K; k0 += 32){
    uint4 xv = *(const uint4*)(X + (size_t)(bm + srow)*K + k0 + scol);
    uint2* xd = (uint2*)(Xs + srow*40 + scol);
    xd[0] = make_uint2(xv.x, xv.y); xd[1] = make_uint2(xv.z, xv.w);
    const float* wp = W + (size_t)(bn + srow)*K + k0 + scol;
    float4 wa = ((const float4*)wp)[0], wb = ((const float4*)wp)[1];
    uint2* wd = (uint2*)(Ws + srow*40 + scol);
    wd[0] = make_uint2(f2b2(wa.x, wa.y), f2b2(wa.z, wa.w));
    wd[1] = make_uint2(f2b2(wb.x, wb.y), f2b2(wb.z, wb.w));
    __syncthreads();
    FragU af[2], bf_[2];
    #pragma unroll
    for (int tm = 0; tm < 2; ++tm){
      const bf16* p = Xs + (mw*32 + tm*16 + r16)*40 + quad*8;
      af[tm].d[0] = *(const uint2*)p; af[tm].d[1] = *(const uint2*)(p + 4);
    }
    #pragma unroll
    for (int tn = 0; tn < 2; ++tn){
      const bf16* p = Ws + (nw*32 + tn*16 + r16)*40 + quad*8;
      bf_[tn].d[0] = *(const uint2*)p; bf_[tn].d[1] = *(const uint2*)(p + 4);
    }
    #pragma unroll
    for (int tm = 0; tm < 2; ++tm)
      #pragma unroll
      for (int tn = 0; tn < 2; ++tn)
        acc[tm][tn] = __builtin_amdgcn_mfma_f32_16x16x32_bf16(af[tm].s, bf_[tn].s, acc[tm][tn], 0, 0, 0);
    __syncthreads();
  }
  #pragma unroll
  for (int tm = 0; tm < 2; ++tm){
    #pragma unroll
    for (int tn = 0; tn < 2; ++tn){
      int n = bn + nw*32 + tn*16 + r16;
      float bb = bias[n];
      #pragma unroll
      for (int r = 0; r < 4; ++r){
        int m = bm + mw*32 + tm*16 + quad*4 + r;
        float v = acc[tm][tn][r] + bb;
        if (ACT == 1) v = tanhf(v);
        else if (ACT == 2) v = 0.5f*v*(1.0f + erff(v*0.70710678118f));
        else if (ACT == 3) v = fmaxf(v, 0.f);
        if (add) v += add_scale * add[(size_t)m*N + n];
        sto(out, (size_t)m*N + n, v);
      }
    }
  }
}

// ---------------- token build + pos embedding -> h f32 [4800,128] ----------------
__global__ __launch_bounds__(256) void token_kernel(
    const float* __restrict__ rtgs, const int* __restrict__ actions, const int* __restrict__ timesteps,
    const float* __restrict__ ret_w, const float* __restrict__ ret_b, const float* __restrict__ act_tab,
    const float* __restrict__ pos_emb, const float* __restrict__ gpe,
    const float* __restrict__ se, float* __restrict__ h)
{
  int idx = blockIdx.x*256 + threadIdx.x;   // 4800*128
  int c = idx & 127; int row = idx >> 7;
  int s = row % 150; int b = row / 150;
  int t = s / 3; int r = s - 3*t;
  float tok;
  if (r == 0)      tok = tanhf(rtgs[b*50+t] * ret_w[c] + ret_b[c]);
  else if (r == 1) tok = se[(b*50+t)*128 + c];
  else             tok = tanhf(act_tab[actions[b*50+t]*128 + c]);
  float pe = gpe[(size_t)timesteps[b]*128 + c] + pos_emb[s*128 + c];
  h[idx] = tok + pe;
}

// ---------------- LayerNorm over C=128 -> bf16 outputs ----------------
__global__ __launch_bounds__(256) void ln_kernel(
    const float* __restrict__ x,
    const float* __restrict__ g1, const float* __restrict__ be1, bf16* __restrict__ o1,
    const float* __restrict__ g2, const float* __restrict__ be2, bf16* o2)
{
  int lane = threadIdx.x & 63;
  int row = blockIdx.x*4 + (threadIdx.x >> 6);
  const float2 xv = *(const float2*)(x + (size_t)row*128 + lane*2);
  float s = xv.x + xv.y, sq = xv.x*xv.x + xv.y*xv.y;
  #pragma unroll
  for (int off = 32; off; off >>= 1){ s += __shfl_xor(s, off); sq += __shfl_xor(sq, off); }
  float mean = s * 0.0078125f;
  float var  = sq * 0.0078125f - mean*mean;
  float rstd = rsqrtf(var + 1e-5f);
  float n0 = (xv.x - mean)*rstd, n1 = (xv.y - mean)*rstd;
  int c0 = lane*2;
  ((unsigned int*)o1)[row*64 + lane] = f2b2(n0*g1[c0] + be1[c0], n1*g1[c0+1] + be1[c0+1]);
  if (o2)
    ((unsigned int*)o2)[row*64 + lane] = f2b2(n0*g2[c0] + be2[c0], n1*g2[c0+1] + be2[c0+1]);
}

// ---------------- attention: qkv bf16 [4800,384] (k|q|v), causal, online softmax ----------------
__global__ __launch_bounds__(256) void attn_kernel(const bf16* __restrict__ qkv, bf16* __restrict__ y)
{
  int bh = blockIdx.x;          // 32*8
  int hh = bh & 7; int b = bh >> 3;
  __shared__ float ks[150*16];
  __shared__ float vs[150*16];
  int t = threadIdx.x;
  for (int i = t; i < 2400; i += 256){
    int s = i >> 4; int d = i & 15;
    const bf16* base = qkv + (size_t)(b*150 + s)*384;
    ks[i] = b2f(base[hh*16 + d]);
    vs[i] = b2f(base[256 + hh*16 + d]);
  }
  __syncthreads();
  if (t < 150){
    const bf16* qr = qkv + (size_t)(b*150 + t)*384 + 128 + hh*16;
    float q[16];
    #pragma unroll
    for (int d = 0; d < 16; ++d) q[d] = b2f(qr[d]) * 0.25f;
    float m = -1e30f, l = 0.f, acc[16] = {};
    for (int j = 0; j <= t; ++j){
      const float* kr = ks + j*16;
      float s = 0.f;
      #pragma unroll
      for (int d = 0; d < 16; ++d) s += q[d]*kr[d];
      float mn = fmaxf(m, s);
      float corr = __expf(m - mn);
      float p = __expf(s - mn);
      l = l*corr + p;
      const float* vr = vs + j*16;
      #pragma unroll
      for (int d = 0; d < 16; ++d) acc[d] = acc[d]*corr + p*vr[d];
      m = mn;
    }
    float inv = 1.f / l;
    bf16* yr = y + (size_t)(b*150 + t)*128 + hh*16;
    #pragma unroll
    for (int d = 0; d < 16; ++d) yr[d] = __float2bfloat16(acc[d]*inv);
  }
}

// ---------------- fused final LN + head on state tokens -> f32 [1600,18] ----------------
__global__ __launch_bounds__(64) void head_kernel(
    const float* __restrict__ h, const float* __restrict__ g, const float* __restrict__ be,
    const float* __restrict__ hw, float* __restrict__ out)
{
  int bt = blockIdx.x;
  int lane = threadIdx.x;
  int b = bt / 50, t = bt % 50;
  const float* row = h + ((size_t)b*150 + 3*t + 1)*128;
  float2 xv = *(const float2*)(row + lane*2);
  float s = xv.x + xv.y, sq = xv.x*xv.x + xv.y*xv.y;
  #pragma unroll
  for (int off = 32; off; off >>= 1){ s += __shfl_xor(s, off); sq += __shfl_xor(sq, off); }
  float mean = s * 0.0078125f;
  float var  = sq * 0.0078125f - mean*mean;
  float rstd = rsqrtf(var + 1e-5f);
  int c0 = lane*2;
  __shared__ float sh[128];
  sh[c0]   = (xv.x-mean)*rstd*g[c0]   + be[c0];
  sh[c0+1] = (xv.y-mean)*rstd*g[c0+1] + be[c0+1];
  __syncthreads();
  if (lane < 18){
    const float* wr = hw + lane*128;
    float acc = 0.f;
    #pragma unroll
    for (int c = 0; c < 128; c += 4){
      float4 wf = *(const float4*)(wr + c);
      acc += sh[c]*wf.x + sh[c+1]*wf.y + sh[c+2]*wf.z + sh[c+3]*wf.w;
    }
    out[bt*18 + lane] = acc;
  }
}

// ---------------- launch ----------------
extern "C" void kernel_launch(void* const* d_in, const int* in_sizes, int n_in,
                              void* d_out, int out_size, void* d_ws, size_t ws_size,
                              hipStream_t stream)
{
  const float* states    = (const float*)d_in[0];
  const float* rtgs      = (const float*)d_in[1];
  const int*   actions   = (const int*)d_in[2];
  const int*   timesteps = (const int*)d_in[3];
  const float* pos_emb   = (const float*)d_in[5];
  const float* gpe       = (const float*)d_in[6];
  const float* c1_w = (const float*)d_in[7];  const float* c1_b = (const float*)d_in[8];
  const float* c2_w = (const float*)d_in[9];  const float* c2_b = (const float*)d_in[10];
  const float* c3_w = (const float*)d_in[11]; const float* c3_b = (const float*)d_in[12];
  const float* enc_w = (const float*)d_in[13]; const float* enc_b = (const float*)d_in[14];
  const float* ret_w = (const float*)d_in[15]; const float* ret_b = (const float*)d_in[16];
  const float* act_tab = (const float*)d_in[17];
  const float* ln_w = (const float*)d_in[18]; const float* ln_b = (const float*)d_in[19];
  const float* attn_w = (const float*)d_in[20]; const float* attn_b = (const float*)d_in[21];
  const float* mlp_w1 = (const float*)d_in[22]; const float* mlp_b1 = (const float*)d_in[23];
  const float* mlp_w2 = (const float*)d_in[24]; const float* mlp_b2 = (const float*)d_in[25];
  const float* ad_dw = (const float*)d_in[26]; const float* ad_db = (const float*)d_in[27];
  const float* ad_uw = (const float*)d_in[28]; const float* ad_ub = (const float*)d_in[29];
  const float* lnf_w = (const float*)d_in[30]; const float* lnf_b = (const float*)d_in[31];
  const float* head_w = (const float*)d_in[32];
  float* out = (float*)d_out;

  char* ws = (char*)d_ws;
  bf16* c1o  = (bf16*)(ws + OFF_C1);
  bf16* c2o  = (bf16*)(ws + OFF_C2);
  bf16* c3o  = (bf16*)(ws + OFF_C3);
  float* se  = (float*)(ws + OFF_SE);
  float* h   = (float*)(ws + OFF_H);
  bf16* xa   = (bf16*)(ws + OFF_XA);
  bf16* nrm  = (bf16*)(ws + OFF_NORM);
  bf16* qkv  = (bf16*)(ws + OFF_QKV);
  bf16* y    = (bf16*)(ws + OFF_Y);
  float* h1  = (float*)(ws + OFF_H1);
  bf16* mlph = (bf16*)(ws + OFF_MLPH);
  bf16* adh  = (bf16*)(ws + OFF_ADH);
  bf16* wtb  = (bf16*)(ws + OFF_WT);    // conv3 wt: 73728 B over dead conv1 output
  bf16* wt1  = (bf16*)(ws + OFF_WT1);   // conv1 wt: 16384 B over dead conv2 output

  c1wt_kernel<<<32, 256, 0, stream>>>(c1_w, wt1);         // c2o region dead now
  conv1_kernel<<<6400, 256, 0, stream>>>(states, wt1, c1_b, c1o);
  conv2_kernel<<<1600, 256, 0, stream>>>(c1o, c2_w, c2_b, c2o);
  wt_kernel<<<144, 256, 0, stream>>>(c3_w, wtb);          // c1o dead now
  conv3_kernel<<<1600, 256, 0, stream>>>(c2o, wtb, c3_b, c3o);
  // state_e = tanh(c3o @ enc_w^T + enc_b): M=1600, N=128, K=3136
  mgemm<1, float><<<25*2, 256, 0, stream>>>(c3o, enc_w, enc_b, nullptr, 0.f, se, 1600, 128, 3136);
  token_kernel<<<2400, 256, 0, stream>>>(rtgs, actions, timesteps, ret_w, ret_b, act_tab,
                                         pos_emb, gpe, se, h);

  for (int l = 0; l < 6; ++l){
    const float* g1 = ln_w + (l*3+0)*128; const float* be1 = ln_b + (l*3+0)*128;
    const float* g2 = ln_w + (l*3+1)*128; const float* be2 = ln_b + (l*3+1)*128;
    const float* g3 = ln_w + (l*3+2)*128; const float* be3 = ln_b + (l*3+2)*128;
    ln_kernel<<<1200, 256, 0, stream>>>(h, g1, be1, xa, g3, be3, nrm);
    mgemm<0, bf16><<<75*6, 256, 0, stream>>>(xa, attn_w + (size_t)l*4*16384, attn_b + l*4*128,
                                             nullptr, 0.f, qkv, 4800, 384, 128);
    attn_kernel<<<256, 256, 0, stream>>>(qkv, y);
    mgemm<0, float><<<75*2, 256, 0, stream>>>(y, attn_w + ((size_t)l*4+3)*16384, attn_b + (l*4+3)*128,
                                              h, 1.0f, h1, 4800, 128, 128);
    ln_kernel<<<1200, 256, 0, stream>>>(h1, g2, be2, xa, nullptr, nullptr, nullptr);
    mgemm<2, bf16><<<75*8, 256, 0, stream>>>(xa, mlp_w1 + (size_t)l*65536, mlp_b1 + l*512,
                                             nullptr, 0.f, mlph, 4800, 512, 128);
    mgemm<3, bf16><<<75*1, 256, 0, stream>>>(nrm, ad_dw + (size_t)l*8192, ad_db + l*64,
                                             nullptr, 0.f, adh, 4800, 64, 128);
    mgemm<0, float><<<75*2, 256, 0, stream>>>(mlph, mlp_w2 + (size_t)l*65536, mlp_b2 + l*128,
                                              h1, 2.0f, h, 4800, 128, 512);
    mgemm<0, float><<<75*2, 256, 0, stream>>>(adh, ad_uw + (size_t)l*8192, ad_ub + l*128,
                                              h, 1.0f, h, 4800, 128, 64);
  }
  head_kernel<<<1600, 64, 0, stream>>>(h, lnf_w, lnf_b, head_w, out);
}

// Round 7
// 1081.639 us; speedup vs baseline: 1.0136x; 1.0136x over previous
//
#include <hip/hip_runtime.h>
#include <hip/hip_bf16.h>
#include <math.h>

typedef __hip_bfloat16 bf16;

typedef __attribute__((ext_vector_type(8))) short bfrag;
typedef __attribute__((ext_vector_type(4))) float f32x4;
union FragU { bfrag s; uint2 d[2]; unsigned int u[4]; };

static __device__ __forceinline__ float b2f(bf16 x){ return __bfloat162float(x); }
// pack two floats into a bf16x2 uint
static __device__ __forceinline__ unsigned int f2b2(float lo, float hi){
  bf16 l = __float2bfloat16(lo), h = __float2bfloat16(hi);
  unsigned short lb, hb;
  __builtin_memcpy(&lb, &l, 2); __builtin_memcpy(&hb, &h, 2);
  return (unsigned int)lb | ((unsigned int)hb << 16);
}
static __device__ __forceinline__ void sto(float* p, size_t i, float v){ p[i] = v; }
static __device__ __forceinline__ void sto(bf16* p, size_t i, float v){ p[i] = __float2bfloat16(v); }

// ---------------- workspace layout (bytes) ----------------
constexpr size_t MiB = 1ull << 20;
constexpr size_t OFF_C1   = 0;         // bf16 [1600,32,20,20] 40.96 MB
constexpr size_t OFF_C2   = 41*MiB;    // bf16 [1600,64,9,9]
constexpr size_t OFF_C3   = 58*MiB;    // bf16 [1600,3136]
constexpr size_t OFF_SE   = 69*MiB;    // f32  [1600,128]
constexpr size_t OFF_H    = 0;         // f32  [4800,128]
constexpr size_t OFF_QKV  = 9*MiB;     // bf16 [4800,384]
constexpr size_t OFF_Y    = 17*MiB;    // bf16 [4800,128]
constexpr size_t OFF_H1   = 20*MiB;    // f32  [4800,128]
constexpr size_t OFF_MLPH = 23*MiB;    // bf16 [4800,512]
constexpr size_t OFF_ADH  = 33*MiB;    // bf16 [4800,64]
// conv3 weight table (bf16 [64][576], k = tap*64+c) parked at offset 3MiB (dead
// region during conv stage; clobbered later by transformer buffers -> consumed first).
constexpr size_t OFF_WT   = 3*MiB;
// conv1 weight table (bf16 [32][256], linear cvt) parked at OFF_C2:
// written BEFORE conv1 (c2 region dead), consumed by conv1, overwritten by conv2.
constexpr size_t OFF_WT1  = OFF_C2;

// ---------------- conv1 weight repack: f32 [32][256] -> bf16 [32][256] (same layout) ----------------
__global__ __launch_bounds__(256) void c1wt_kernel(const float* __restrict__ w, bf16* __restrict__ wt)
{
  int i = blockIdx.x*256 + threadIdx.x;   // 8192
  wt[i] = __float2bfloat16(w[i]);
}

// ================= conv1 via implicit-im2col MFMA, direct-global A (R4 variant, 110us) =================
// x f32 [1600,4,84,84] -> relu -> bf16 [1600,32,20,20]
// GEMM per image: M=400, N=32, K=256 (c*64+ky*8+kx). A-fragment = two aligned
// float4 global loads (L2/L3 absorbs the ~4x re-read). No barrier in K-loop.
// Structural latency floor ~110us established over R1-R6 (occupancy, DMA,
// DMA+occupancy all within 110-132); accepted -- further gain needs counted-vmcnt
// cross-tile pipelining (T3/T4 inline asm).
__global__ __launch_bounds__(256) void conv1_kernel(
    const float* __restrict__ x, const bf16* __restrict__ wt,
    const float* __restrict__ bias, bf16* __restrict__ out)
{
  __shared__ bf16 ost[32*408];      // out-stage [32][408 pad]
  int b = blockIdx.x;
  int t = threadIdx.x;
  int lane = t & 63, wave = t >> 6;
  int quad = lane >> 4, r16 = lane & 15;
  const float* xb = x + (size_t)b*28224;
  const float* pb[7];
  #pragma unroll
  for (int i = 0; i < 7; ++i){
    int tile = wave*7 + i; if (tile > 24) tile = 24;
    int m = tile*16 + r16;
    int oy = m / 20, ox = m % 20;
    pb[i] = xb + 4*oy*84 + 4*ox;
  }
  f32x4 acc[7][2];
  #pragma unroll
  for (int i = 0; i < 7; ++i)
    #pragma unroll
    for (int j = 0; j < 2; ++j) acc[i][j] = (f32x4){0.f,0.f,0.f,0.f};
  for (int kc = 0; kc < 8; ++kc){
    int c = kc >> 1, ky = (kc & 1)*4 + quad;
    int off = c*7056 + ky*84;
    FragU bf_[2];
    #pragma unroll
    for (int tn = 0; tn < 2; ++tn){
      uint4 wv = *(const uint4*)(wt + (tn*16 + r16)*256 + kc*32 + quad*8);
      bf_[tn].u[0] = wv.x; bf_[tn].u[1] = wv.y; bf_[tn].u[2] = wv.z; bf_[tn].u[3] = wv.w;
    }
    #pragma unroll
    for (int i = 0; i < 7; ++i){
      if (wave*7 + i < 25){
        const float* p = pb[i] + off;
        float4 fa = *(const float4*)p;
        float4 fb = *(const float4*)(p + 4);
        FragU a;
        a.u[0] = f2b2(fa.x, fa.y); a.u[1] = f2b2(fa.z, fa.w);
        a.u[2] = f2b2(fb.x, fb.y); a.u[3] = f2b2(fb.z, fb.w);
        acc[i][0] = __builtin_amdgcn_mfma_f32_16x16x32_bf16(a.s, bf_[0].s, acc[i][0], 0, 0, 0);
        acc[i][1] = __builtin_amdgcn_mfma_f32_16x16x32_bf16(a.s, bf_[1].s, acc[i][1], 0, 0, 0);
      }
    }
  }
  #pragma unroll
  for (int i = 0; i < 7; ++i){
    int tile = wave*7 + i;
    if (tile < 25){
      int m0 = tile*16 + quad*4;
      #pragma unroll
      for (int tn = 0; tn < 2; ++tn){
        int oc = tn*16 + r16;
        float bb = bias[oc];
        float v0 = fmaxf(acc[i][tn][0] + bb, 0.f);
        float v1 = fmaxf(acc[i][tn][1] + bb, 0.f);
        float v2 = fmaxf(acc[i][tn][2] + bb, 0.f);
        float v3 = fmaxf(acc[i][tn][3] + bb, 0.f);
        *(uint2*)(ost + oc*408 + m0) = make_uint2(f2b2(v0, v1), f2b2(v2, v3));
      }
    }
  }
  __syncthreads();
  bf16* outp = out + (size_t)b*12800;
  for (int e = t; e < 1600; e += 256){
    int oc = e / 50, col = e % 50;
    uint4 v = *(const uint4*)(ost + oc*408 + col*8);
    *(uint4*)(outp + oc*400 + col*8) = v;
  }
}

// ================= conv2 via implicit-im2col MFMA =================
// x bf16 [1600,32,20,20] -> relu -> bf16 [1600,64,9,9]
__global__ __launch_bounds__(256) void conv2_kernel(
    const bf16* __restrict__ x, const float* __restrict__ w,
    const float* __restrict__ bias, bf16* __restrict__ out)
{
  __shared__ bf16 xs2[32*20*24];    // [c][row][24 pad]; reused as out-stage [64][81]
  int b = blockIdx.x;
  int t = threadIdx.x;
  const unsigned int* xb = (const unsigned int*)(x + (size_t)b*12800);
  for (int p = t; p < 6400; p += 256){
    int c = p / 200, rem = p % 200;
    int r = rem / 10, cp = rem % 10;
    ((unsigned int*)xs2)[((c*20 + r)*24 + 2*cp) >> 1] = xb[p];
  }
  __syncthreads();
  int lane = t & 63, wave = t >> 6;
  int quad = lane >> 4, r16 = lane & 15;
  int oc = wave*16 + r16;
  f32x4 acc[6];
  #pragma unroll
  for (int i = 0; i < 6; ++i) acc[i] = (f32x4){0.f,0.f,0.f,0.f};
  for (int kc = 0; kc < 16; ++kc){
    const float* wp = w + oc*512 + kc*32 + quad*8;
    float4 wa = ((const float4*)wp)[0], wb = ((const float4*)wp)[1];
    FragU bfr;
    bfr.u[0] = f2b2(wa.x, wa.y); bfr.u[1] = f2b2(wa.z, wa.w);
    bfr.u[2] = f2b2(wb.x, wb.y); bfr.u[3] = f2b2(wb.z, wb.w);
    int c = kc*2 + (quad >> 1);
    int ky0 = (quad & 1)*2;
    #pragma unroll
    for (int tile = 0; tile < 6; ++tile){
      int m = tile*16 + r16; if (m > 80) m = 80;
      int oy = m / 9, ox = m % 9;
      int idx1 = (c*20 + 2*oy + ky0)*24 + 2*ox;
      const unsigned int* q1 = (const unsigned int*)(xs2 + idx1);
      const unsigned int* q2 = (const unsigned int*)(xs2 + idx1 + 24);
      FragU a;
      a.u[0] = q1[0]; a.u[1] = q1[1];
      a.u[2] = q2[0]; a.u[3] = q2[1];
      acc[tile] = __builtin_amdgcn_mfma_f32_16x16x32_bf16(a.s, bfr.s, acc[tile], 0, 0, 0);
    }
  }
  __syncthreads();
  float bb = bias[oc];
  #pragma unroll
  for (int tile = 0; tile < 6; ++tile){
    #pragma unroll
    for (int r = 0; r < 4; ++r){
      int m = tile*16 + quad*4 + r;
      if (m < 81){
        float v = fmaxf(acc[tile][r] + bb, 0.f);
        xs2[oc*81 + m] = __float2bfloat16(v);
      }
    }
  }
  __syncthreads();
  const unsigned int* lsu = (const unsigned int*)xs2;
  unsigned int* op = (unsigned int*)(out + (size_t)b*5184);
  for (int e = t; e < 2592; e += 256) op[e] = lsu[e];
}

// ---------------- conv3 weight repack: f32 [64][64][3][3] -> bf16 [64][576] k'=tap*64+c ----------------
__global__ __launch_bounds__(256) void wt_kernel(const float* __restrict__ w, bf16* __restrict__ wt)
{
  int o = blockIdx.x*256 + threadIdx.x;   // 36864 = 144*256
  int oc = o / 576, r = o % 576;
  int tap = r >> 6, c = r & 63;
  wt[o] = __float2bfloat16(w[oc*576 + c*9 + tap]);
}

// ================= conv3 via implicit-im2col MFMA =================
// x bf16 [1600,64,9,9] -> relu -> bf16 [1600,64,7,7]->[1600,3136]
__global__ __launch_bounds__(256) void conv3_kernel(
    const bf16* __restrict__ x, const bf16* __restrict__ wt,
    const float* __restrict__ bias, bf16* __restrict__ out)
{
  __shared__ ushort lin[5184];      // native [c][81]; reused as out-stage [64][49]
  __shared__ ushort xt[81*72];      // [p][c], stride 72
  int b = blockIdx.x;
  int t = threadIdx.x;
  const uint2* xb = (const uint2*)(x + (size_t)b*5184);
  for (int i = t; i < 1296; i += 256) ((uint2*)lin)[i] = xb[i];
  __syncthreads();
  for (int e = t; e < 5184; e += 256){
    int c = e & 63, p = e >> 6;
    xt[p*72 + c] = lin[c*81 + p];
  }
  __syncthreads();
  int lane = t & 63, wv = t >> 6;
  int quad = lane >> 4, r16 = lane & 15;
  int m = wv*16 + r16;
  int pos = m < 49 ? m : 48;
  int pb = (pos/7)*9 + (pos%7);
  const ushort* abase = xt + pb*72 + quad*8;
  const bf16* wb0 = wt + (size_t)r16*576 + quad*8;
  f32x4 acc[4];
  #pragma unroll
  for (int tn = 0; tn < 4; ++tn) acc[tn] = (f32x4){0.f,0.f,0.f,0.f};
  #pragma unroll 3
  for (int kc = 0; kc < 18; ++kc){
    int tap = kc >> 1;
    int toff = (tap/3)*9 + (tap%3);
    int soff = toff*72 + (kc & 1)*32;
    FragU a;
    uint4 av = *(const uint4*)(abase + soff);
    a.u[0] = av.x; a.u[1] = av.y; a.u[2] = av.z; a.u[3] = av.w;
    #pragma unroll
    for (int tn = 0; tn < 4; ++tn){
      uint4 bv = *(const uint4*)(wb0 + tn*9216 + kc*32);
      FragU bfr;
      bfr.u[0] = bv.x; bfr.u[1] = bv.y; bfr.u[2] = bv.z; bfr.u[3] = bv.w;
      acc[tn] = __builtin_amdgcn_mfma_f32_16x16x32_bf16(a.s, bfr.s, acc[tn], 0, 0, 0);
    }
  }
  __syncthreads();
  #pragma unroll
  for (int tn = 0; tn < 4; ++tn){
    int oc = tn*16 + r16;
    float bb = bias[oc];
    #pragma unroll
    for (int r = 0; r < 4; ++r){
      int p = wv*16 + quad*4 + r;
      if (p < 49){
        bf16 v = __float2bfloat16(fmaxf(acc[tn][r] + bb, 0.f));
        ushort u; __builtin_memcpy(&u, &v, 2);
        lin[oc*49 + p] = u;
      }
    }
  }
  __syncthreads();
  uint2* op = (uint2*)(out + (size_t)b*3136);
  for (int e = t; e < 784; e += 256) op[e] = ((const uint2*)lin)[e];
}

// ================= generic MFMA GEMM (kept for enc: K=3136) =================
template<int ACT, typename OT>
__global__ __launch_bounds__(256) void mgemm(
    const bf16* __restrict__ X, const float* __restrict__ W,
    const float* __restrict__ bias, const float* __restrict__ add, float add_scale,
    OT* __restrict__ out, int M, int N, int K)
{
  __shared__ bf16 Xs[64*40];
  __shared__ bf16 Ws[64*40];
  int nb = N >> 6;
  int bn = (blockIdx.x % nb) << 6;
  int bm = (blockIdx.x / nb) << 6;
  int t = threadIdx.x;
  int lane = t & 63, wave = t >> 6;
  int mw = wave >> 1, nw = wave & 1;
  int quad = lane >> 4, r16 = lane & 15;
  int srow = t >> 2, scol = (t & 3)*8;
  f32x4 acc[2][2];
  #pragma unroll
  for (int i = 0; i < 2; ++i)
    #pragma unroll
    for (int j = 0; j < 2; ++j) acc[i][j] = (f32x4){0.f,0.f,0.f,0.f};
  for (int k0 = 0; k0 < K; k0 += 32){
    uint4 xv = *(const uint4*)(X + (size_t)(bm + srow)*K + k0 + scol);
    uint2* xd = (uint2*)(Xs + srow*40 + scol);
    xd[0] = make_uint2(xv.x, xv.y); xd[1] = make_uint2(xv.z, xv.w);
    const float* wp = W + (size_t)(bn + srow)*K + k0 + scol;
    float4 wa = ((const float4*)wp)[0], wb = ((const float4*)wp)[1];
    uint2* wd = (uint2*)(Ws + srow*40 + scol);
    wd[0] = make_uint2(f2b2(wa.x, wa.y), f2b2(wa.z, wa.w));
    wd[1] = make_uint2(f2b2(wb.x, wb.y), f2b2(wb.z, wb.w));
    __syncthreads();
    FragU af[2], bf_[2];
    #pragma unroll
    for (int tm = 0; tm < 2; ++tm){
      const bf16* p = Xs + (mw*32 + tm*16 + r16)*40 + quad*8;
      af[tm].d[0] = *(const uint2*)p; af[tm].d[1] = *(const uint2*)(p + 4);
    }
    #pragma unroll
    for (int tn = 0; tn < 2; ++tn){
      const bf16* p = Ws + (nw*32 + tn*16 + r16)*40 + quad*8;
      bf_[tn].d[0] = *(const uint2*)p; bf_[tn].d[1] = *(const uint2*)(p + 4);
    }
    #pragma unroll
    for (int tm = 0; tm < 2; ++tm)
      #pragma unroll
      for (int tn = 0; tn < 2; ++tn)
        acc[tm][tn] = __builtin_amdgcn_mfma_f32_16x16x32_bf16(af[tm].s, bf_[tn].s, acc[tm][tn], 0, 0, 0);
    __syncthreads();
  }
  #pragma unroll
  for (int tm = 0; tm < 2; ++tm){
    #pragma unroll
    for (int tn = 0; tn < 2; ++tn){
      int n = bn + nw*32 + tn*16 + r16;
      float bb = bias[n];
      #pragma unroll
      for (int r = 0; r < 4; ++r){
        int m = bm + mw*32 + tm*16 + quad*4 + r;
        float v = acc[tm][tn][r] + bb;
        if (ACT == 1) v = tanhf(v);
        else if (ACT == 2) v = 0.5f*v*(1.0f + erff(v*0.70710678118f));
        else if (ACT == 3) v = fmaxf(v, 0.f);
        if (add) v += add_scale * add[(size_t)m*N + n];
        sto(out, (size_t)m*N + n, v);
      }
    }
  }
}

// ================= K=128 single-stage MFMA GEMM, optional fused LayerNorm =================
// LNF=1: X f32 [M,128], LN(g,be) computed in-kernel during stage (4-lane shfl reduce).
// LNF=0: X bf16 [M,128] loaded directly.
// Full X and W tiles staged once -> ONE barrier total (vs 8 in k-loop mgemm).
// out = ACT(LN(X) @ W^T + bias) + add_scale*add. Xs/Ws row stride 136 (bank-spread).
template<int ACT, int LNF, typename OT>
__global__ __launch_bounds__(256) void mgemm128(
    const void* __restrict__ Xv, const float* __restrict__ g, const float* __restrict__ be,
    const float* __restrict__ W, const float* __restrict__ bias,
    const float* __restrict__ add, float add_scale,
    OT* __restrict__ out, int M, int N)
{
  __shared__ bf16 Xs[64*136];
  __shared__ bf16 Ws[64*136];
  int nb = N >> 6;
  int bn = (blockIdx.x % nb) << 6;
  int bm = (blockIdx.x / nb) << 6;
  int t = threadIdx.x;
  int row = t >> 2, cch = (t & 3) << 5;    // 4 threads/row, 32-col chunks
  // --- stage X (+ optional LN) ---
  if (LNF){
    const float* xr = (const float*)Xv + (size_t)(bm + row)*128 + cch;
    float4 xv[8];
    #pragma unroll
    for (int i = 0; i < 8; ++i) xv[i] = ((const float4*)xr)[i];
    float s = 0.f, sq = 0.f;
    #pragma unroll
    for (int i = 0; i < 8; ++i){
      s  += xv[i].x + xv[i].y + xv[i].z + xv[i].w;
      sq += xv[i].x*xv[i].x + xv[i].y*xv[i].y + xv[i].z*xv[i].z + xv[i].w*xv[i].w;
    }
    s += __shfl_xor(s, 1); sq += __shfl_xor(sq, 1);
    s += __shfl_xor(s, 2); sq += __shfl_xor(sq, 2);
    float mean = s * 0.0078125f;
    float var  = sq * 0.0078125f - mean*mean;
    float rstd = rsqrtf(var + 1e-5f);
    unsigned int* xd = (unsigned int*)(Xs + row*136 + cch);
    #pragma unroll
    for (int i = 0; i < 8; ++i){
      int c = cch + i*4;
      float a0 = (xv[i].x - mean)*rstd*g[c]   + be[c];
      float a1 = (xv[i].y - mean)*rstd*g[c+1] + be[c+1];
      float a2 = (xv[i].z - mean)*rstd*g[c+2] + be[c+2];
      float a3 = (xv[i].w - mean)*rstd*g[c+3] + be[c+3];
      xd[2*i] = f2b2(a0, a1); xd[2*i+1] = f2b2(a2, a3);
    }
  } else {
    const uint4* xr = (const uint4*)((const bf16*)Xv + (size_t)(bm + row)*128 + cch);
    uint4* xd = (uint4*)(Xs + row*136 + cch);
    #pragma unroll
    for (int i = 0; i < 4; ++i) xd[i] = xr[i];
  }
  // --- stage W (f32 -> bf16) ---
  {
    const float* wr = W + (size_t)(bn + row)*128 + cch;
    unsigned int* wd = (unsigned int*)(Ws + row*136 + cch);
    #pragma unroll
    for (int i = 0; i < 8; ++i){
      float4 wv = ((const float4*)wr)[i];
      wd[2*i] = f2b2(wv.x, wv.y); wd[2*i+1] = f2b2(wv.z, wv.w);
    }
  }
  __syncthreads();
  // --- compute: 4 K-slices, no barriers ---
  int lane = t & 63, wave = t >> 6;
  int mw = wave >> 1, nw = wave & 1;
  int quad = lane >> 4, r16 = lane & 15;
  f32x4 acc[2][2];
  #pragma unroll
  for (int i = 0; i < 2; ++i)
    #pragma unroll
    for (int j = 0; j < 2; ++j) acc[i][j] = (f32x4){0.f,0.f,0.f,0.f};
  #pragma unroll
  for (int k0 = 0; k0 < 128; k0 += 32){
    FragU af[2], bf_[2];
    #pragma unroll
    for (int tm = 0; tm < 2; ++tm){
      const bf16* p = Xs + (mw*32 + tm*16 + r16)*136 + k0 + quad*8;
      af[tm].d[0] = *(const uint2*)p; af[tm].d[1] = *(const uint2*)(p + 4);
    }
    #pragma unroll
    for (int tn = 0; tn < 2; ++tn){
      const bf16* p = Ws + (nw*32 + tn*16 + r16)*136 + k0 + quad*8;
      bf_[tn].d[0] = *(const uint2*)p; bf_[tn].d[1] = *(const uint2*)(p + 4);
    }
    #pragma unroll
    for (int tm = 0; tm < 2; ++tm)
      #pragma unroll
      for (int tn = 0; tn < 2; ++tn)
        acc[tm][tn] = __builtin_amdgcn_mfma_f32_16x16x32_bf16(af[tm].s, bf_[tn].s, acc[tm][tn], 0, 0, 0);
  }
  // --- epilogue ---
  #pragma unroll
  for (int tm = 0; tm < 2; ++tm){
    #pragma unroll
    for (int tn = 0; tn < 2; ++tn){
      int n = bn + nw*32 + tn*16 + r16;
      float bb = bias[n];
      #pragma unroll
      for (int r = 0; r < 4; ++r){
        int m = bm + mw*32 + tm*16 + quad*4 + r;
        float v = acc[tm][tn][r] + bb;
        if (ACT == 1) v = tanhf(v);
        else if (ACT == 2) v = 0.5f*v*(1.0f + erff(v*0.70710678118f));
        else if (ACT == 3) v = fmaxf(v, 0.f);
        if (add) v += add_scale * add[(size_t)m*N + n];
        sto(out, (size_t)m*N + n, v);
      }
    }
  }
}

// ================= dual-input accumulating GEMM: h = X1@W1^T + X2@W2^T + b1 + b2 + add_scale*add =================
// X1 bf16 [M,512] (gelu-act mlp hidden), X2 bf16 [M,64] (adapter hidden).
// W1 f32 [N,512], W2 f32 [N,64]. Replaces mlp2 + adapter-up (2 dispatches + h RMW).
__global__ __launch_bounds__(256) void mgemm_dual(
    const bf16* __restrict__ X1, const float* __restrict__ W1,
    const bf16* __restrict__ X2, const float* __restrict__ W2,
    const float* __restrict__ b1, const float* __restrict__ b2,
    const float* __restrict__ add, float add_scale,
    float* __restrict__ out, int M, int N)
{
  __shared__ bf16 Xs[64*40];
  __shared__ bf16 Ws[64*40];
  int nb = N >> 6;
  int bn = (blockIdx.x % nb) << 6;
  int bm = (blockIdx.x / nb) << 6;
  int t = threadIdx.x;
  int lane = t & 63, wave = t >> 6;
  int mw = wave >> 1, nw = wave & 1;
  int quad = lane >> 4, r16 = lane & 15;
  int srow = t >> 2, scol = (t & 3)*8;
  f32x4 acc[2][2];
  #pragma unroll
  for (int i = 0; i < 2; ++i)
    #pragma unroll
    for (int j = 0; j < 2; ++j) acc[i][j] = (f32x4){0.f,0.f,0.f,0.f};
  for (int kk = 0; kk < 18; ++kk){
    const bf16* X; const float* W; int K; int k0;
    if (kk < 16){ X = X1; W = W1; K = 512; k0 = kk*32; }
    else        { X = X2; W = W2; K = 64;  k0 = (kk - 16)*32; }
    uint4 xv = *(const uint4*)(X + (size_t)(bm + srow)*K + k0 + scol);
    uint2* xd = (uint2*)(Xs + srow*40 + scol);
    xd[0] = make_uint2(xv.x, xv.y); xd[1] = make_uint2(xv.z, xv.w);
    const float* wp = W + (size_t)(bn + srow)*K + k0 + scol;
    float4 wa = ((const float4*)wp)[0], wb = ((const float4*)wp)[1];
    uint2* wd = (uint2*)(Ws + srow*40 + scol);
    wd[0] = make_uint2(f2b2(wa.x, wa.y), f2b2(wa.z, wa.w));
    wd[1] = make_uint2(f2b2(wb.x, wb.y), f2b2(wb.z, wb.w));
    __syncthreads();
    FragU af[2], bf_[2];
    #pragma unroll
    for (int tm = 0; tm < 2; ++tm){
      const bf16* p = Xs + (mw*32 + tm*16 + r16)*40 + quad*8;
      af[tm].d[0] = *(const uint2*)p; af[tm].d[1] = *(const uint2*)(p + 4);
    }
    #pragma unroll
    for (int tn = 0; tn < 2; ++tn){
      const bf16* p = Ws + (nw*32 + tn*16 + r16)*40 + quad*8;
      bf_[tn].d[0] = *(const uint2*)p; bf_[tn].d[1] = *(const uint2*)(p + 4);
    }
    #pragma unroll
    for (int tm = 0; tm < 2; ++tm)
      #pragma unroll
      for (int tn = 0; tn < 2; ++tn)
        acc[tm][tn] = __builtin_amdgcn_mfma_f32_16x16x32_bf16(af[tm].s, bf_[tn].s, acc[tm][tn], 0, 0, 0);
    __syncthreads();
  }
  #pragma unroll
  for (int tm = 0; tm < 2; ++tm){
    #pragma unroll
    for (int tn = 0; tn < 2; ++tn){
      int n = bn + nw*32 + tn*16 + r16;
      float bb = b1[n] + b2[n];
      #pragma unroll
      for (int r = 0; r < 4; ++r){
        int m = bm + mw*32 + tm*16 + quad*4 + r;
        out[(size_t)m*N + n] = acc[tm][tn][r] + bb + add_scale * add[(size_t)m*N + n];
      }
    }
  }
}

// ---------------- token build + pos embedding -> h f32 [4800,128] ----------------
__global__ __launch_bounds__(256) void token_kernel(
    const float* __restrict__ rtgs, const int* __restrict__ actions, const int* __restrict__ timesteps,
    const float* __restrict__ ret_w, const float* __restrict__ ret_b, const float* __restrict__ act_tab,
    const float* __restrict__ pos_emb, const float* __restrict__ gpe,
    const float* __restrict__ se, float* __restrict__ h)
{
  int idx = blockIdx.x*256 + threadIdx.x;   // 4800*128
  int c = idx & 127; int row = idx >> 7;
  int s = row % 150; int b = row / 150;
  int t = s / 3; int r = s - 3*t;
  float tok;
  if (r == 0)      tok = tanhf(rtgs[b*50+t] * ret_w[c] + ret_b[c]);
  else if (r == 1) tok = se[(b*50+t)*128 + c];
  else             tok = tanhf(act_tab[actions[b*50+t]*128 + c]);
  float pe = gpe[(size_t)timesteps[b]*128 + c] + pos_emb[s*128 + c];
  h[idx] = tok + pe;
}

// ---------------- attention: qkv bf16 [4800,384] (k|q|v), causal, online softmax ----------------
__global__ __launch_bounds__(256) void attn_kernel(const bf16* __restrict__ qkv, bf16* __restrict__ y)
{
  int bh = blockIdx.x;          // 32*8
  int hh = bh & 7; int b = bh >> 3;
  __shared__ float ks[150*16];
  __shared__ float vs[150*16];
  int t = threadIdx.x;
  for (int i = t; i < 2400; i += 256){
    int s = i >> 4; int d = i & 15;
    const bf16* base = qkv + (size_t)(b*150 + s)*384;
    ks[i] = b2f(base[hh*16 + d]);
    vs[i] = b2f(base[256 + hh*16 + d]);
  }
  __syncthreads();
  if (t < 150){
    const bf16* qr = qkv + (size_t)(b*150 + t)*384 + 128 + hh*16;
    float q[16];
    #pragma unroll
    for (int d = 0; d < 16; ++d) q[d] = b2f(qr[d]) * 0.25f;
    float m = -1e30f, l = 0.f, acc[16] = {};
    for (int j = 0; j <= t; ++j){
      const float* kr = ks + j*16;
      float s = 0.f;
      #pragma unroll
      for (int d = 0; d < 16; ++d) s += q[d]*kr[d];
      float mn = fmaxf(m, s);
      float corr = __expf(m - mn);
      float p = __expf(s - mn);
      l = l*corr + p;
      const float* vr = vs + j*16;
      #pragma unroll
      for (int d = 0; d < 16; ++d) acc[d] = acc[d]*corr + p*vr[d];
      m = mn;
    }
    float inv = 1.f / l;
    bf16* yr = y + (size_t)(b*150 + t)*128 + hh*16;
    #pragma unroll
    for (int d = 0; d < 16; ++d) yr[d] = __float2bfloat16(acc[d]*inv);
  }
}

// ---------------- fused final LN + head on state tokens -> f32 [1600,18] ----------------
__global__ __launch_bounds__(64) void head_kernel(
    const float* __restrict__ h, const float* __restrict__ g, const float* __restrict__ be,
    const float* __restrict__ hw, float* __restrict__ out)
{
  int bt = blockIdx.x;
  int lane = threadIdx.x;
  int b = bt / 50, t = bt % 50;
  const float* row = h + ((size_t)b*150 + 3*t + 1)*128;
  float2 xv = *(const float2*)(row + lane*2);
  float s = xv.x + xv.y, sq = xv.x*xv.x + xv.y*xv.y;
  #pragma unroll
  for (int off = 32; off; off >>= 1){ s += __shfl_xor(s, off); sq += __shfl_xor(sq, off); }
  float mean = s * 0.0078125f;
  float var  = sq * 0.0078125f - mean*mean;
  float rstd = rsqrtf(var + 1e-5f);
  int c0 = lane*2;
  __shared__ float sh[128];
  sh[c0]   = (xv.x-mean)*rstd*g[c0]   + be[c0];
  sh[c0+1] = (xv.y-mean)*rstd*g[c0+1] + be[c0+1];
  __syncthreads();
  if (lane < 18){
    const float* wr = hw + lane*128;
    float acc = 0.f;
    #pragma unroll
    for (int c = 0; c < 128; c += 4){
      float4 wf = *(const float4*)(wr + c);
      acc += sh[c]*wf.x + sh[c+1]*wf.y + sh[c+2]*wf.z + sh[c+3]*wf.w;
    }
    out[bt*18 + lane] = acc;
  }
}

// ---------------- launch ----------------
extern "C" void kernel_launch(void* const* d_in, const int* in_sizes, int n_in,
                              void* d_out, int out_size, void* d_ws, size_t ws_size,
                              hipStream_t stream)
{
  const float* states    = (const float*)d_in[0];
  const float* rtgs      = (const float*)d_in[1];
  const int*   actions   = (const int*)d_in[2];
  const int*   timesteps = (const int*)d_in[3];
  const float* pos_emb   = (const float*)d_in[5];
  const float* gpe       = (const float*)d_in[6];
  const float* c1_w = (const float*)d_in[7];  const float* c1_b = (const float*)d_in[8];
  const float* c2_w = (const float*)d_in[9];  const float* c2_b = (const float*)d_in[10];
  const float* c3_w = (const float*)d_in[11]; const float* c3_b = (const float*)d_in[12];
  const float* enc_w = (const float*)d_in[13]; const float* enc_b = (const float*)d_in[14];
  const float* ret_w = (const float*)d_in[15]; const float* ret_b = (const float*)d_in[16];
  const float* act_tab = (const float*)d_in[17];
  const float* ln_w = (const float*)d_in[18]; const float* ln_b = (const float*)d_in[19];
  const float* attn_w = (const float*)d_in[20]; const float* attn_b = (const float*)d_in[21];
  const float* mlp_w1 = (const float*)d_in[22]; const float* mlp_b1 = (const float*)d_in[23];
  const float* mlp_w2 = (const float*)d_in[24]; const float* mlp_b2 = (const float*)d_in[25];
  const float* ad_dw = (const float*)d_in[26]; const float* ad_db = (const float*)d_in[27];
  const float* ad_uw = (const float*)d_in[28]; const float* ad_ub = (const float*)d_in[29];
  const float* lnf_w = (const float*)d_in[30]; const float* lnf_b = (const float*)d_in[31];
  const float* head_w = (const float*)d_in[32];
  float* out = (float*)d_out;

  char* ws = (char*)d_ws;
  bf16* c1o  = (bf16*)(ws + OFF_C1);
  bf16* c2o  = (bf16*)(ws + OFF_C2);
  bf16* c3o  = (bf16*)(ws + OFF_C3);
  float* se  = (float*)(ws + OFF_SE);
  float* h   = (float*)(ws + OFF_H);
  bf16* qkv  = (bf16*)(ws + OFF_QKV);
  bf16* y    = (bf16*)(ws + OFF_Y);
  float* h1  = (float*)(ws + OFF_H1);
  bf16* mlph = (bf16*)(ws + OFF_MLPH);
  bf16* adh  = (bf16*)(ws + OFF_ADH);
  bf16* wtb  = (bf16*)(ws + OFF_WT);    // conv3 wt: 73728 B (dead region during conv stage)
  bf16* wt1  = (bf16*)(ws + OFF_WT1);   // conv1 wt: 16384 B over dead conv2 output

  c1wt_kernel<<<32, 256, 0, stream>>>(c1_w, wt1);
  conv1_kernel<<<1600, 256, 0, stream>>>(states, wt1, c1_b, c1o);
  conv2_kernel<<<1600, 256, 0, stream>>>(c1o, c2_w, c2_b, c2o);
  wt_kernel<<<144, 256, 0, stream>>>(c3_w, wtb);
  conv3_kernel<<<1600, 256, 0, stream>>>(c2o, wtb, c3_b, c3o);
  // state_e = tanh(c3o @ enc_w^T + enc_b): M=1600, N=128, K=3136
  mgemm<1, float><<<25*2, 256, 0, stream>>>(c3o, enc_w, enc_b, nullptr, 0.f, se, 1600, 128, 3136);
  token_kernel<<<2400, 256, 0, stream>>>(rtgs, actions, timesteps, ret_w, ret_b, act_tab,
                                         pos_emb, gpe, se, h);

  for (int l = 0; l < 6; ++l){
    const float* g1 = ln_w + (l*3+0)*128; const float* be1 = ln_b + (l*3+0)*128;
    const float* g2 = ln_w + (l*3+1)*128; const float* be2 = ln_b + (l*3+1)*128;
    const float* g3 = ln_w + (l*3+2)*128; const float* be3 = ln_b + (l*3+2)*128;
    // qkv = LN1(h) @ Wkqv^T + b   (N=384)
    mgemm128<0, 1, bf16><<<75*6, 256, 0, stream>>>(h, g1, be1,
        attn_w + (size_t)l*4*16384, attn_b + l*4*128, nullptr, 0.f, qkv, 4800, 384);
    attn_kernel<<<256, 256, 0, stream>>>(qkv, y);
    // h1 = y @ Wproj^T + b3 + h   (N=128)
    mgemm128<0, 0, float><<<75*2, 256, 0, stream>>>(y, nullptr, nullptr,
        attn_w + ((size_t)l*4+3)*16384, attn_b + (l*4+3)*128, h, 1.0f, h1, 4800, 128);
    // mlph = gelu(LN2(h1) @ W1^T + b1)   (N=512)
    mgemm128<2, 1, bf16><<<75*8, 256, 0, stream>>>(h1, g2, be2,
        mlp_w1 + (size_t)l*65536, mlp_b1 + l*512, nullptr, 0.f, mlph, 4800, 512);
    // adh = relu(LN3(h_pre) @ Wad^T + db)   (N=64) -- h still pre-layer here
    mgemm128<3, 1, bf16><<<75*1, 256, 0, stream>>>(h, g3, be3,
        ad_dw + (size_t)l*8192, ad_db + l*64, nullptr, 0.f, adh, 4800, 64);
    // h = mlph@W2^T + adh@Wu^T + b2 + ub + 2*h1   (N=128)
    mgemm_dual<<<75*2, 256, 0, stream>>>(mlph, mlp_w2 + (size_t)l*65536,
        adh, ad_uw + (size_t)l*8192, mlp_b2 + l*128, ad_ub + l*128,
        h1, 2.0f, h, 4800, 128);
  }
  head_kernel<<<1600, 64, 0, stream>>>(h, lnf_w, lnf_b, head_w, out);
}

// Round 8
// 1028.490 us; speedup vs baseline: 1.0660x; 1.0517x over previous
//
#include <hip/hip_runtime.h>
#include <hip/hip_bf16.h>
#include <math.h>

typedef __hip_bfloat16 bf16;

typedef __attribute__((ext_vector_type(8))) short bfrag;
typedef __attribute__((ext_vector_type(4))) float f32x4;
union FragU { bfrag s; uint2 d[2]; unsigned int u[4]; };

static __device__ __forceinline__ float b2f(bf16 x){ return __bfloat162float(x); }
// pack two floats into a bf16x2 uint
static __device__ __forceinline__ unsigned int f2b2(float lo, float hi){
  bf16 l = __float2bfloat16(lo), h = __float2bfloat16(hi);
  unsigned short lb, hb;
  __builtin_memcpy(&lb, &l, 2); __builtin_memcpy(&hb, &h, 2);
  return (unsigned int)lb | ((unsigned int)hb << 16);
}
static __device__ __forceinline__ void sto(float* p, size_t i, float v){ p[i] = v; }
static __device__ __forceinline__ void sto(bf16* p, size_t i, float v){ p[i] = __float2bfloat16(v); }

// ---------------- workspace layout (bytes) ----------------
constexpr size_t MiB = 1ull << 20;
constexpr size_t OFF_C1   = 0;         // bf16 [1600,32,20,20] 40.96 MB
constexpr size_t OFF_C2   = 41*MiB;    // bf16 [1600,64,9,9] (dead after conv3 -> reused for bf16 weights)
constexpr size_t OFF_C3   = 58*MiB;    // bf16 [1600,3136]
constexpr size_t OFF_SE   = 69*MiB;    // f32  [1600,128]
constexpr size_t OFF_H    = 0;         // f32  [4800,128]
constexpr size_t OFF_QKV  = 9*MiB;     // bf16 [4800,384]
constexpr size_t OFF_Y    = 17*MiB;    // bf16 [4800,128]
constexpr size_t OFF_H1   = 20*MiB;    // f32  [4800,128]
constexpr size_t OFF_MLPH = 23*MiB;    // bf16 [4800,512]
constexpr size_t OFF_ADH  = 33*MiB;    // bf16 [4800,64]
// conv3 weight table (bf16 [64][576]) parked at 3MiB (dead during conv stage).
constexpr size_t OFF_WT   = 3*MiB;
// conv1 weight table parked at OFF_C2 (consumed by conv1 before conv2 writes).
constexpr size_t OFF_WT1  = OFF_C2;
// bf16 transformer weights, parked over dead conv2 output (written after conv3):
constexpr size_t OFF_WB   = OFF_C2;            // element offsets within (bf16*)(ws+OFF_WB):
constexpr size_t WB_ATTN  = 0;                 // [6][4][128][128] = 393216
constexpr size_t WB_M1    = 393216;            // [6][512][128]    = 393216
constexpr size_t WB_M2    = 786432;            // [6][128][512]    = 393216
constexpr size_t WB_AD    = 1179648;           // [6][64][128]     = 49152
constexpr size_t WB_AU    = 1228800;           // [6][128][64]     = 49152  (end 1277952 el = 2.56MB)

// ---------------- generic f32 -> bf16 weight convert ----------------
__global__ __launch_bounds__(256) void wcvt_kernel(const float* __restrict__ w, bf16* __restrict__ o, int n)
{
  int i = blockIdx.x*256 + threadIdx.x;
  if (i < n) o[i] = __float2bfloat16(w[i]);
}

// ---------------- conv1 weight repack: f32 [32][256] -> bf16 (same layout) ----------------
__global__ __launch_bounds__(256) void c1wt_kernel(const float* __restrict__ w, bf16* __restrict__ wt)
{
  int i = blockIdx.x*256 + threadIdx.x;   // 8192
  wt[i] = __float2bfloat16(w[i]);
}

// ================= conv1 via implicit-im2col MFMA, direct-global A (R4 variant, ~107us) =================
// Structural latency floor established over R1-R6; accepted.
__global__ __launch_bounds__(256) void conv1_kernel(
    const float* __restrict__ x, const bf16* __restrict__ wt,
    const float* __restrict__ bias, bf16* __restrict__ out)
{
  __shared__ bf16 ost[32*408];      // out-stage [32][408 pad]
  int b = blockIdx.x;
  int t = threadIdx.x;
  int lane = t & 63, wave = t >> 6;
  int quad = lane >> 4, r16 = lane & 15;
  const float* xb = x + (size_t)b*28224;
  const float* pb[7];
  #pragma unroll
  for (int i = 0; i < 7; ++i){
    int tile = wave*7 + i; if (tile > 24) tile = 24;
    int m = tile*16 + r16;
    int oy = m / 20, ox = m % 20;
    pb[i] = xb + 4*oy*84 + 4*ox;
  }
  f32x4 acc[7][2];
  #pragma unroll
  for (int i = 0; i < 7; ++i)
    #pragma unroll
    for (int j = 0; j < 2; ++j) acc[i][j] = (f32x4){0.f,0.f,0.f,0.f};
  for (int kc = 0; kc < 8; ++kc){
    int c = kc >> 1, ky = (kc & 1)*4 + quad;
    int off = c*7056 + ky*84;
    FragU bf_[2];
    #pragma unroll
    for (int tn = 0; tn < 2; ++tn){
      uint4 wv = *(const uint4*)(wt + (tn*16 + r16)*256 + kc*32 + quad*8);
      bf_[tn].u[0] = wv.x; bf_[tn].u[1] = wv.y; bf_[tn].u[2] = wv.z; bf_[tn].u[3] = wv.w;
    }
    #pragma unroll
    for (int i = 0; i < 7; ++i){
      if (wave*7 + i < 25){
        const float* p = pb[i] + off;
        float4 fa = *(const float4*)p;
        float4 fb = *(const float4*)(p + 4);
        FragU a;
        a.u[0] = f2b2(fa.x, fa.y); a.u[1] = f2b2(fa.z, fa.w);
        a.u[2] = f2b2(fb.x, fb.y); a.u[3] = f2b2(fb.z, fb.w);
        acc[i][0] = __builtin_amdgcn_mfma_f32_16x16x32_bf16(a.s, bf_[0].s, acc[i][0], 0, 0, 0);
        acc[i][1] = __builtin_amdgcn_mfma_f32_16x16x32_bf16(a.s, bf_[1].s, acc[i][1], 0, 0, 0);
      }
    }
  }
  #pragma unroll
  for (int i = 0; i < 7; ++i){
    int tile = wave*7 + i;
    if (tile < 25){
      int m0 = tile*16 + quad*4;
      #pragma unroll
      for (int tn = 0; tn < 2; ++tn){
        int oc = tn*16 + r16;
        float bb = bias[oc];
        float v0 = fmaxf(acc[i][tn][0] + bb, 0.f);
        float v1 = fmaxf(acc[i][tn][1] + bb, 0.f);
        float v2 = fmaxf(acc[i][tn][2] + bb, 0.f);
        float v3 = fmaxf(acc[i][tn][3] + bb, 0.f);
        *(uint2*)(ost + oc*408 + m0) = make_uint2(f2b2(v0, v1), f2b2(v2, v3));
      }
    }
  }
  __syncthreads();
  bf16* outp = out + (size_t)b*12800;
  for (int e = t; e < 1600; e += 256){
    int oc = e / 50, col = e % 50;
    uint4 v = *(const uint4*)(ost + oc*408 + col*8);
    *(uint4*)(outp + oc*400 + col*8) = v;
  }
}

// ================= conv2 via implicit-im2col MFMA =================
__global__ __launch_bounds__(256) void conv2_kernel(
    const bf16* __restrict__ x, const float* __restrict__ w,
    const float* __restrict__ bias, bf16* __restrict__ out)
{
  __shared__ bf16 xs2[32*20*24];    // [c][row][24 pad]; reused as out-stage [64][81]
  int b = blockIdx.x;
  int t = threadIdx.x;
  const unsigned int* xb = (const unsigned int*)(x + (size_t)b*12800);
  for (int p = t; p < 6400; p += 256){
    int c = p / 200, rem = p % 200;
    int r = rem / 10, cp = rem % 10;
    ((unsigned int*)xs2)[((c*20 + r)*24 + 2*cp) >> 1] = xb[p];
  }
  __syncthreads();
  int lane = t & 63, wave = t >> 6;
  int quad = lane >> 4, r16 = lane & 15;
  int oc = wave*16 + r16;
  f32x4 acc[6];
  #pragma unroll
  for (int i = 0; i < 6; ++i) acc[i] = (f32x4){0.f,0.f,0.f,0.f};
  for (int kc = 0; kc < 16; ++kc){
    const float* wp = w + oc*512 + kc*32 + quad*8;
    float4 wa = ((const float4*)wp)[0], wb = ((const float4*)wp)[1];
    FragU bfr;
    bfr.u[0] = f2b2(wa.x, wa.y); bfr.u[1] = f2b2(wa.z, wa.w);
    bfr.u[2] = f2b2(wb.x, wb.y); bfr.u[3] = f2b2(wb.z, wb.w);
    int c = kc*2 + (quad >> 1);
    int ky0 = (quad & 1)*2;
    #pragma unroll
    for (int tile = 0; tile < 6; ++tile){
      int m = tile*16 + r16; if (m > 80) m = 80;
      int oy = m / 9, ox = m % 9;
      int idx1 = (c*20 + 2*oy + ky0)*24 + 2*ox;
      const unsigned int* q1 = (const unsigned int*)(xs2 + idx1);
      const unsigned int* q2 = (const unsigned int*)(xs2 + idx1 + 24);
      FragU a;
      a.u[0] = q1[0]; a.u[1] = q1[1];
      a.u[2] = q2[0]; a.u[3] = q2[1];
      acc[tile] = __builtin_amdgcn_mfma_f32_16x16x32_bf16(a.s, bfr.s, acc[tile], 0, 0, 0);
    }
  }
  __syncthreads();
  float bb = bias[oc];
  #pragma unroll
  for (int tile = 0; tile < 6; ++tile){
    #pragma unroll
    for (int r = 0; r < 4; ++r){
      int m = tile*16 + quad*4 + r;
      if (m < 81){
        float v = fmaxf(acc[tile][r] + bb, 0.f);
        xs2[oc*81 + m] = __float2bfloat16(v);
      }
    }
  }
  __syncthreads();
  const unsigned int* lsu = (const unsigned int*)xs2;
  unsigned int* op = (unsigned int*)(out + (size_t)b*5184);
  for (int e = t; e < 2592; e += 256) op[e] = lsu[e];
}

// ---------------- conv3 weight repack: f32 [64][64][3][3] -> bf16 [64][576] k'=tap*64+c ----------------
__global__ __launch_bounds__(256) void wt_kernel(const float* __restrict__ w, bf16* __restrict__ wt)
{
  int o = blockIdx.x*256 + threadIdx.x;   // 36864 = 144*256
  int oc = o / 576, r = o % 576;
  int tap = r >> 6, c = r & 63;
  wt[o] = __float2bfloat16(w[oc*576 + c*9 + tap]);
}

// ================= conv3 via implicit-im2col MFMA =================
__global__ __launch_bounds__(256) void conv3_kernel(
    const bf16* __restrict__ x, const bf16* __restrict__ wt,
    const float* __restrict__ bias, bf16* __restrict__ out)
{
  __shared__ ushort lin[5184];
  __shared__ ushort xt[81*72];
  int b = blockIdx.x;
  int t = threadIdx.x;
  const uint2* xb = (const uint2*)(x + (size_t)b*5184);
  for (int i = t; i < 1296; i += 256) ((uint2*)lin)[i] = xb[i];
  __syncthreads();
  for (int e = t; e < 5184; e += 256){
    int c = e & 63, p = e >> 6;
    xt[p*72 + c] = lin[c*81 + p];
  }
  __syncthreads();
  int lane = t & 63, wv = t >> 6;
  int quad = lane >> 4, r16 = lane & 15;
  int m = wv*16 + r16;
  int pos = m < 49 ? m : 48;
  int pb = (pos/7)*9 + (pos%7);
  const ushort* abase = xt + pb*72 + quad*8;
  const bf16* wb0 = wt + (size_t)r16*576 + quad*8;
  f32x4 acc[4];
  #pragma unroll
  for (int tn = 0; tn < 4; ++tn) acc[tn] = (f32x4){0.f,0.f,0.f,0.f};
  #pragma unroll 3
  for (int kc = 0; kc < 18; ++kc){
    int tap = kc >> 1;
    int toff = (tap/3)*9 + (tap%3);
    int soff = toff*72 + (kc & 1)*32;
    FragU a;
    uint4 av = *(const uint4*)(abase + soff);
    a.u[0] = av.x; a.u[1] = av.y; a.u[2] = av.z; a.u[3] = av.w;
    #pragma unroll
    for (int tn = 0; tn < 4; ++tn){
      uint4 bv = *(const uint4*)(wb0 + tn*9216 + kc*32);
      FragU bfr;
      bfr.u[0] = bv.x; bfr.u[1] = bv.y; bfr.u[2] = bv.z; bfr.u[3] = bv.w;
      acc[tn] = __builtin_amdgcn_mfma_f32_16x16x32_bf16(a.s, bfr.s, acc[tn], 0, 0, 0);
    }
  }
  __syncthreads();
  #pragma unroll
  for (int tn = 0; tn < 4; ++tn){
    int oc = tn*16 + r16;
    float bb = bias[oc];
    #pragma unroll
    for (int r = 0; r < 4; ++r){
      int p = wv*16 + quad*4 + r;
      if (p < 49){
        bf16 v = __float2bfloat16(fmaxf(acc[tn][r] + bb, 0.f));
        ushort u; __builtin_memcpy(&u, &v, 2);
        lin[oc*49 + p] = u;
      }
    }
  }
  __syncthreads();
  uint2* op = (uint2*)(out + (size_t)b*3136);
  for (int e = t; e < 784; e += 256) op[e] = ((const uint2*)lin)[e];
}

// ================= generic MFMA GEMM (kept for enc: K=3136, runs once) =================
template<int ACT, typename OT>
__global__ __launch_bounds__(256) void mgemm(
    const bf16* __restrict__ X, const float* __restrict__ W,
    const float* __restrict__ bias, const float* __restrict__ add, float add_scale,
    OT* __restrict__ out, int M, int N, int K)
{
  __shared__ bf16 Xs[64*40];
  __shared__ bf16 Ws[64*40];
  int nb = N >> 6;
  int bn = (blockIdx.x % nb) << 6;
  int bm = (blockIdx.x / nb) << 6;
  int t = threadIdx.x;
  int lane = t & 63, wave = t >> 6;
  int mw = wave >> 1, nw = wave & 1;
  int quad = lane >> 4, r16 = lane & 15;
  int srow = t >> 2, scol = (t & 3)*8;
  f32x4 acc[2][2];
  #pragma unroll
  for (int i = 0; i < 2; ++i)
    #pragma unroll
    for (int j = 0; j < 2; ++j) acc[i][j] = (f32x4){0.f,0.f,0.f,0.f};
  for (int k0 = 0; k0 < K; k0 += 32){
    uint4 xv = *(const uint4*)(X + (size_t)(bm + srow)*K + k0 + scol);
    uint2* xd = (uint2*)(Xs + srow*40 + scol);
    xd[0] = make_uint2(xv.x, xv.y); xd[1] = make_uint2(xv.z, xv.w);
    const float* wp = W + (size_t)(bn + srow)*K + k0 + scol;
    float4 wa = ((const float4*)wp)[0], wb = ((const float4*)wp)[1];
    uint2* wd = (uint2*)(Ws + srow*40 + scol);
    wd[0] = make_uint2(f2b2(wa.x, wa.y), f2b2(wa.z, wa.w));
    wd[1] = make_uint2(f2b2(wb.x, wb.y), f2b2(wb.z, wb.w));
    __syncthreads();
    FragU af[2], bf_[2];
    #pragma unroll
    for (int tm = 0; tm < 2; ++tm){
      const bf16* p = Xs + (mw*32 + tm*16 + r16)*40 + quad*8;
      af[tm].d[0] = *(const uint2*)p; af[tm].d[1] = *(const uint2*)(p + 4);
    }
    #pragma unroll
    for (int tn = 0; tn < 2; ++tn){
      const bf16* p = Ws + (nw*32 + tn*16 + r16)*40 + quad*8;
      bf_[tn].d[0] = *(const uint2*)p; bf_[tn].d[1] = *(const uint2*)(p + 4);
    }
    #pragma unroll
    for (int tm = 0; tm < 2; ++tm)
      #pragma unroll
      for (int tn = 0; tn < 2; ++tn)
        acc[tm][tn] = __builtin_amdgcn_mfma_f32_16x16x32_bf16(af[tm].s, bf_[tn].s, acc[tm][tn], 0, 0, 0);
    __syncthreads();
  }
  #pragma unroll
  for (int tm = 0; tm < 2; ++tm){
    #pragma unroll
    for (int tn = 0; tn < 2; ++tn){
      int n = bn + nw*32 + tn*16 + r16;
      float bb = bias[n];
      #pragma unroll
      for (int r = 0; r < 4; ++r){
        int m = bm + mw*32 + tm*16 + quad*4 + r;
        float v = acc[tm][tn][r] + bb;
        if (ACT == 1) v = tanhf(v);
        else if (ACT == 2) v = 0.5f*v*(1.0f + erff(v*0.70710678118f));
        else if (ACT == 3) v = fmaxf(v, 0.f);
        if (add) v += add_scale * add[(size_t)m*N + n];
        sto(out, (size_t)m*N + n, v);
      }
    }
  }
}

// ================= K=128 single-stage MFMA GEMM, bf16 W, optional fused LayerNorm =================
// LNF=1: X f32 [M,128], LN(g,be) computed in-kernel during stage (4-lane shfl reduce).
// LNF=0: X bf16 [M,128]. W bf16 [N,128] (pre-converted once by wcvt_kernel).
// Full X and W staged once -> ONE barrier total.
template<int ACT, int LNF, typename OT>
__global__ __launch_bounds__(256) void mgemm128(
    const void* __restrict__ Xv, const float* __restrict__ g, const float* __restrict__ be,
    const bf16* __restrict__ W, const float* __restrict__ bias,
    const float* __restrict__ add, float add_scale,
    OT* __restrict__ out, int M, int N)
{
  __shared__ bf16 Xs[64*136];
  __shared__ bf16 Ws[64*136];
  int nb = N >> 6;
  int bn = (blockIdx.x % nb) << 6;
  int bm = (blockIdx.x / nb) << 6;
  int t = threadIdx.x;
  int row = t >> 2, cch = (t & 3) << 5;    // 4 threads/row, 32-col chunks
  // --- stage X (+ optional LN) ---
  if (LNF){
    const float* xr = (const float*)Xv + (size_t)(bm + row)*128 + cch;
    float4 xv[8];
    #pragma unroll
    for (int i = 0; i < 8; ++i) xv[i] = ((const float4*)xr)[i];
    float s = 0.f, sq = 0.f;
    #pragma unroll
    for (int i = 0; i < 8; ++i){
      s  += xv[i].x + xv[i].y + xv[i].z + xv[i].w;
      sq += xv[i].x*xv[i].x + xv[i].y*xv[i].y + xv[i].z*xv[i].z + xv[i].w*xv[i].w;
    }
    s += __shfl_xor(s, 1); sq += __shfl_xor(sq, 1);
    s += __shfl_xor(s, 2); sq += __shfl_xor(sq, 2);
    float mean = s * 0.0078125f;
    float var  = sq * 0.0078125f - mean*mean;
    float rstd = rsqrtf(var + 1e-5f);
    unsigned int* xd = (unsigned int*)(Xs + row*136 + cch);
    #pragma unroll
    for (int i = 0; i < 8; ++i){
      int c = cch + i*4;
      float a0 = (xv[i].x - mean)*rstd*g[c]   + be[c];
      float a1 = (xv[i].y - mean)*rstd*g[c+1] + be[c+1];
      float a2 = (xv[i].z - mean)*rstd*g[c+2] + be[c+2];
      float a3 = (xv[i].w - mean)*rstd*g[c+3] + be[c+3];
      xd[2*i] = f2b2(a0, a1); xd[2*i+1] = f2b2(a2, a3);
    }
  } else {
    const uint4* xr = (const uint4*)((const bf16*)Xv + (size_t)(bm + row)*128 + cch);
    uint4* xd = (uint4*)(Xs + row*136 + cch);
    #pragma unroll
    for (int i = 0; i < 4; ++i) xd[i] = xr[i];
  }
  // --- stage W (bf16 straight copy) ---
  {
    const uint4* wr = (const uint4*)(W + (size_t)(bn + row)*128 + cch);
    uint4* wd = (uint4*)(Ws + row*136 + cch);
    #pragma unroll
    for (int i = 0; i < 4; ++i) wd[i] = wr[i];
  }
  __syncthreads();
  // --- compute: 4 K-slices, no barriers ---
  int lane = t & 63, wave = t >> 6;
  int mw = wave >> 1, nw = wave & 1;
  int quad = lane >> 4, r16 = lane & 15;
  f32x4 acc[2][2];
  #pragma unroll
  for (int i = 0; i < 2; ++i)
    #pragma unroll
    for (int j = 0; j < 2; ++j) acc[i][j] = (f32x4){0.f,0.f,0.f,0.f};
  #pragma unroll
  for (int k0 = 0; k0 < 128; k0 += 32){
    FragU af[2], bf_[2];
    #pragma unroll
    for (int tm = 0; tm < 2; ++tm){
      const bf16* p = Xs + (mw*32 + tm*16 + r16)*136 + k0 + quad*8;
      af[tm].d[0] = *(const uint2*)p; af[tm].d[1] = *(const uint2*)(p + 4);
    }
    #pragma unroll
    for (int tn = 0; tn < 2; ++tn){
      const bf16* p = Ws + (nw*32 + tn*16 + r16)*136 + k0 + quad*8;
      bf_[tn].d[0] = *(const uint2*)p; bf_[tn].d[1] = *(const uint2*)(p + 4);
    }
    #pragma unroll
    for (int tm = 0; tm < 2; ++tm)
      #pragma unroll
      for (int tn = 0; tn < 2; ++tn)
        acc[tm][tn] = __builtin_amdgcn_mfma_f32_16x16x32_bf16(af[tm].s, bf_[tn].s, acc[tm][tn], 0, 0, 0);
  }
  // --- epilogue ---
  #pragma unroll
  for (int tm = 0; tm < 2; ++tm){
    #pragma unroll
    for (int tn = 0; tn < 2; ++tn){
      int n = bn + nw*32 + tn*16 + r16;
      float bb = bias[n];
      #pragma unroll
      for (int r = 0; r < 4; ++r){
        int m = bm + mw*32 + tm*16 + quad*4 + r;
        float v = acc[tm][tn][r] + bb;
        if (ACT == 1) v = tanhf(v);
        else if (ACT == 2) v = 0.5f*v*(1.0f + erff(v*0.70710678118f));
        else if (ACT == 3) v = fmaxf(v, 0.f);
        if (add) v += add_scale * add[(size_t)m*N + n];
        sto(out, (size_t)m*N + n, v);
      }
    }
  }
}

// ================= dual-input accumulating GEMM (bf16 W): h = X1@W1^T + X2@W2^T + b1+b2 + s*add =================
__global__ __launch_bounds__(256) void mgemm_dual(
    const bf16* __restrict__ X1, const bf16* __restrict__ W1,
    const bf16* __restrict__ X2, const bf16* __restrict__ W2,
    const float* __restrict__ b1, const float* __restrict__ b2,
    const float* __restrict__ add, float add_scale,
    float* __restrict__ out, int M, int N)
{
  __shared__ bf16 Xs[64*40];
  __shared__ bf16 Ws[64*40];
  int nb = N >> 6;
  int bn = (blockIdx.x % nb) << 6;
  int bm = (blockIdx.x / nb) << 6;
  int t = threadIdx.x;
  int lane = t & 63, wave = t >> 6;
  int mw = wave >> 1, nw = wave & 1;
  int quad = lane >> 4, r16 = lane & 15;
  int srow = t >> 2, scol = (t & 3)*8;
  f32x4 acc[2][2];
  #pragma unroll
  for (int i = 0; i < 2; ++i)
    #pragma unroll
    for (int j = 0; j < 2; ++j) acc[i][j] = (f32x4){0.f,0.f,0.f,0.f};
  for (int kk = 0; kk < 18; ++kk){
    const bf16* X; const bf16* W; int K; int k0;
    if (kk < 16){ X = X1; W = W1; K = 512; k0 = kk*32; }
    else        { X = X2; W = W2; K = 64;  k0 = (kk - 16)*32; }
    uint4 xv = *(const uint4*)(X + (size_t)(bm + srow)*K + k0 + scol);
    uint2* xd = (uint2*)(Xs + srow*40 + scol);
    xd[0] = make_uint2(xv.x, xv.y); xd[1] = make_uint2(xv.z, xv.w);
    uint4 wv = *(const uint4*)(W + (size_t)(bn + srow)*K + k0 + scol);
    uint2* wd = (uint2*)(Ws + srow*40 + scol);
    wd[0] = make_uint2(wv.x, wv.y); wd[1] = make_uint2(wv.z, wv.w);
    __syncthreads();
    FragU af[2], bf_[2];
    #pragma unroll
    for (int tm = 0; tm < 2; ++tm){
      const bf16* p = Xs + (mw*32 + tm*16 + r16)*40 + quad*8;
      af[tm].d[0] = *(const uint2*)p; af[tm].d[1] = *(const uint2*)(p + 4);
    }
    #pragma unroll
    for (int tn = 0; tn < 2; ++tn){
      const bf16* p = Ws + (nw*32 + tn*16 + r16)*40 + quad*8;
      bf_[tn].d[0] = *(const uint2*)p; bf_[tn].d[1] = *(const uint2*)(p + 4);
    }
    #pragma unroll
    for (int tm = 0; tm < 2; ++tm)
      #pragma unroll
      for (int tn = 0; tn < 2; ++tn)
        acc[tm][tn] = __builtin_amdgcn_mfma_f32_16x16x32_bf16(af[tm].s, bf_[tn].s, acc[tm][tn], 0, 0, 0);
    __syncthreads();
  }
  #pragma unroll
  for (int tm = 0; tm < 2; ++tm){
    #pragma unroll
    for (int tn = 0; tn < 2; ++tn){
      int n = bn + nw*32 + tn*16 + r16;
      float bb = b1[n] + b2[n];
      #pragma unroll
      for (int r = 0; r < 4; ++r){
        int m = bm + mw*32 + tm*16 + quad*4 + r;
        out[(size_t)m*N + n] = acc[tm][tn][r] + bb + add_scale * add[(size_t)m*N + n];
      }
    }
  }
}

// ---------------- token build + pos embedding -> h f32 [4800,128] ----------------
__global__ __launch_bounds__(256) void token_kernel(
    const float* __restrict__ rtgs, const int* __restrict__ actions, const int* __restrict__ timesteps,
    const float* __restrict__ ret_w, const float* __restrict__ ret_b, const float* __restrict__ act_tab,
    const float* __restrict__ pos_emb, const float* __restrict__ gpe,
    const float* __restrict__ se, float* __restrict__ h)
{
  int idx = blockIdx.x*256 + threadIdx.x;   // 4800*128
  int c = idx & 127; int row = idx >> 7;
  int s = row % 150; int b = row / 150;
  int t = s / 3; int r = s - 3*t;
  float tok;
  if (r == 0)      tok = tanhf(rtgs[b*50+t] * ret_w[c] + ret_b[c]);
  else if (r == 1) tok = se[(b*50+t)*128 + c];
  else             tok = tanhf(act_tab[actions[b*50+t]*128 + c]);
  float pe = gpe[(size_t)timesteps[b]*128 + c] + pos_emb[s*128 + c];
  h[idx] = tok + pe;
}

// ---------------- attention: qkv bf16 [4800,384] (k|q|v), causal, online softmax ----------------
__global__ __launch_bounds__(256) void attn_kernel(const bf16* __restrict__ qkv, bf16* __restrict__ y)
{
  int bh = blockIdx.x;          // 32*8
  int hh = bh & 7; int b = bh >> 3;
  __shared__ float ks[150*16];
  __shared__ float vs[150*16];
  int t = threadIdx.x;
  for (int i = t; i < 2400; i += 256){
    int s = i >> 4; int d = i & 15;
    const bf16* base = qkv + (size_t)(b*150 + s)*384;
    ks[i] = b2f(base[hh*16 + d]);
    vs[i] = b2f(base[256 + hh*16 + d]);
  }
  __syncthreads();
  if (t < 150){
    const bf16* qr = qkv + (size_t)(b*150 + t)*384 + 128 + hh*16;
    float q[16];
    #pragma unroll
    for (int d = 0; d < 16; ++d) q[d] = b2f(qr[d]) * 0.25f;
    float m = -1e30f, l = 0.f, acc[16] = {};
    for (int j = 0; j <= t; ++j){
      const float* kr = ks + j*16;
      float s = 0.f;
      #pragma unroll
      for (int d = 0; d < 16; ++d) s += q[d]*kr[d];
      float mn = fmaxf(m, s);
      float corr = __expf(m - mn);
      float p = __expf(s - mn);
      l = l*corr + p;
      const float* vr = vs + j*16;
      #pragma unroll
      for (int d = 0; d < 16; ++d) acc[d] = acc[d]*corr + p*vr[d];
      m = mn;
    }
    float inv = 1.f / l;
    bf16* yr = y + (size_t)(b*150 + t)*128 + hh*16;
    #pragma unroll
    for (int d = 0; d < 16; ++d) yr[d] = __float2bfloat16(acc[d]*inv);
  }
}

// ---------------- fused final LN + head on state tokens -> f32 [1600,18] ----------------
__global__ __launch_bounds__(64) void head_kernel(
    const float* __restrict__ h, const float* __restrict__ g, const float* __restrict__ be,
    const float* __restrict__ hw, float* __restrict__ out)
{
  int bt = blockIdx.x;
  int lane = threadIdx.x;
  int b = bt / 50, t = bt % 50;
  const float* row = h + ((size_t)b*150 + 3*t + 1)*128;
  float2 xv = *(const float2*)(row + lane*2);
  float s = xv.x + xv.y, sq = xv.x*xv.x + xv.y*xv.y;
  #pragma unroll
  for (int off = 32; off; off >>= 1){ s += __shfl_xor(s, off); sq += __shfl_xor(sq, off); }
  float mean = s * 0.0078125f;
  float var  = sq * 0.0078125f - mean*mean;
  float rstd = rsqrtf(var + 1e-5f);
  int c0 = lane*2;
  __shared__ float sh[128];
  sh[c0]   = (xv.x-mean)*rstd*g[c0]   + be[c0];
  sh[c0+1] = (xv.y-mean)*rstd*g[c0+1] + be[c0+1];
  __syncthreads();
  if (lane < 18){
    const float* wr = hw + lane*128;
    float acc = 0.f;
    #pragma unroll
    for (int c = 0; c < 128; c += 4){
      float4 wf = *(const float4*)(wr + c);
      acc += sh[c]*wf.x + sh[c+1]*wf.y + sh[c+2]*wf.z + sh[c+3]*wf.w;
    }
    out[bt*18 + lane] = acc;
  }
}

// ---------------- launch ----------------
extern "C" void kernel_launch(void* const* d_in, const int* in_sizes, int n_in,
                              void* d_out, int out_size, void* d_ws, size_t ws_size,
                              hipStream_t stream)
{
  const float* states    = (const float*)d_in[0];
  const float* rtgs      = (const float*)d_in[1];
  const int*   actions   = (const int*)d_in[2];
  const int*   timesteps = (const int*)d_in[3];
  const float* pos_emb   = (const float*)d_in[5];
  const float* gpe       = (const float*)d_in[6];
  const float* c1_w = (const float*)d_in[7];  const float* c1_b = (const float*)d_in[8];
  const float* c2_w = (const float*)d_in[9];  const float* c2_b = (const float*)d_in[10];
  const float* c3_w = (const float*)d_in[11]; const float* c3_b = (const float*)d_in[12];
  const float* enc_w = (const float*)d_in[13]; const float* enc_b = (const float*)d_in[14];
  const float* ret_w = (const float*)d_in[15]; const float* ret_b = (const float*)d_in[16];
  const float* act_tab = (const float*)d_in[17];
  const float* ln_w = (const float*)d_in[18]; const float* ln_b = (const float*)d_in[19];
  const float* attn_w = (const float*)d_in[20]; const float* attn_b = (const float*)d_in[21];
  const float* mlp_w1 = (const float*)d_in[22]; const float* mlp_b1 = (const float*)d_in[23];
  const float* mlp_w2 = (const float*)d_in[24]; const float* mlp_b2 = (const float*)d_in[25];
  const float* ad_dw = (const float*)d_in[26]; const float* ad_db = (const float*)d_in[27];
  const float* ad_uw = (const float*)d_in[28]; const float* ad_ub = (const float*)d_in[29];
  const float* lnf_w = (const float*)d_in[30]; const float* lnf_b = (const float*)d_in[31];
  const float* head_w = (const float*)d_in[32];
  float* out = (float*)d_out;

  char* ws = (char*)d_ws;
  bf16* c1o  = (bf16*)(ws + OFF_C1);
  bf16* c2o  = (bf16*)(ws + OFF_C2);
  bf16* c3o  = (bf16*)(ws + OFF_C3);
  float* se  = (float*)(ws + OFF_SE);
  float* h   = (float*)(ws + OFF_H);
  bf16* qkv  = (bf16*)(ws + OFF_QKV);
  bf16* y    = (bf16*)(ws + OFF_Y);
  float* h1  = (float*)(ws + OFF_H1);
  bf16* mlph = (bf16*)(ws + OFF_MLPH);
  bf16* adh  = (bf16*)(ws + OFF_ADH);
  bf16* wtb  = (bf16*)(ws + OFF_WT);    // conv3 wt
  bf16* wt1  = (bf16*)(ws + OFF_WT1);   // conv1 wt (over dead conv2 region, consumed before conv2 writes)
  bf16* wb   = (bf16*)(ws + OFF_WB);    // bf16 transformer weights (over dead conv2 output)
  bf16* wbA  = wb + WB_ATTN;
  bf16* wbM1 = wb + WB_M1;
  bf16* wbM2 = wb + WB_M2;
  bf16* wbAD = wb + WB_AD;
  bf16* wbAU = wb + WB_AU;

  c1wt_kernel<<<32, 256, 0, stream>>>(c1_w, wt1);
  conv1_kernel<<<1600, 256, 0, stream>>>(states, wt1, c1_b, c1o);
  conv2_kernel<<<1600, 256, 0, stream>>>(c1o, c2_w, c2_b, c2o);
  wt_kernel<<<144, 256, 0, stream>>>(c3_w, wtb);
  conv3_kernel<<<1600, 256, 0, stream>>>(c2o, wtb, c3_b, c3o);
  // c2o dead now -> convert transformer weights to bf16 into its region
  wcvt_kernel<<<1536, 256, 0, stream>>>(attn_w, wbA, 393216);
  wcvt_kernel<<<1536, 256, 0, stream>>>(mlp_w1, wbM1, 393216);
  wcvt_kernel<<<1536, 256, 0, stream>>>(mlp_w2, wbM2, 393216);
  wcvt_kernel<<<192, 256, 0, stream>>>(ad_dw, wbAD, 49152);
  wcvt_kernel<<<192, 256, 0, stream>>>(ad_uw, wbAU, 49152);
  // state_e = tanh(c3o @ enc_w^T + enc_b): M=1600, N=128, K=3136
  mgemm<1, float><<<25*2, 256, 0, stream>>>(c3o, enc_w, enc_b, nullptr, 0.f, se, 1600, 128, 3136);
  token_kernel<<<2400, 256, 0, stream>>>(rtgs, actions, timesteps, ret_w, ret_b, act_tab,
                                         pos_emb, gpe, se, h);

  for (int l = 0; l < 6; ++l){
    const float* g1 = ln_w + (l*3+0)*128; const float* be1 = ln_b + (l*3+0)*128;
    const float* g2 = ln_w + (l*3+1)*128; const float* be2 = ln_b + (l*3+1)*128;
    const float* g3 = ln_w + (l*3+2)*128; const float* be3 = ln_b + (l*3+2)*128;
    // qkv = LN1(h) @ Wkqv^T + b   (N=384)
    mgemm128<0, 1, bf16><<<75*6, 256, 0, stream>>>(h, g1, be1,
        wbA + (size_t)l*4*16384, attn_b + l*4*128, nullptr, 0.f, qkv, 4800, 384);
    attn_kernel<<<256, 256, 0, stream>>>(qkv, y);
    // h1 = y @ Wproj^T + b3 + h   (N=128)
    mgemm128<0, 0, float><<<75*2, 256, 0, stream>>>(y, nullptr, nullptr,
        wbA + ((size_t)l*4+3)*16384, attn_b + (l*4+3)*128, h, 1.0f, h1, 4800, 128);
    // mlph = gelu(LN2(h1) @ W1^T + b1)   (N=512)
    mgemm128<2, 1, bf16><<<75*8, 256, 0, stream>>>(h1, g2, be2,
        wbM1 + (size_t)l*65536, mlp_b1 + l*512, nullptr, 0.f, mlph, 4800, 512);
    // adh = relu(LN3(h_pre) @ Wad^T + db)   (N=64)
    mgemm128<3, 1, bf16><<<75*1, 256, 0, stream>>>(h, g3, be3,
        wbAD + (size_t)l*8192, ad_db + l*64, nullptr, 0.f, adh, 4800, 64);
    // h = mlph@W2^T + adh@Wu^T + b2 + ub + 2*h1   (N=128)
    mgemm_dual<<<75*2, 256, 0, stream>>>(mlph, wbM2 + (size_t)l*65536,
        adh, wbAU + (size_t)l*8192, mlp_b2 + l*128, ad_ub + l*128,
        h1, 2.0f, h, 4800, 128);
  }
  head_kernel<<<1600, 64, 0, stream>>>(h, lnf_w, lnf_b, head_w, out);
}